// Round 5
// baseline (226.965 us; speedup 1.0000x reference)
//
#include <hip/hip_runtime.h>

namespace {

constexpr int NB = 8, NP = 8192, NC = 91;
constexpr int KTOP = 1000, NDET = 100;
constexpr int MROWS = 1024;          // padded mask rows per image (16 windows of 64)
constexpr int SLOTS = 24;            // max candidates/proposal: scores sum<=1 => <=19 can be >0.05
constexpr int PB = 128;              // proposals per k_candidates block
constexpr int NBUCK = 4096, SORTN = 4096;
constexpr float SCORE_T = 0.05f;
constexpr float MIN_SZ = 0.01f;
constexpr float NMS_T = 0.5f;
constexpr float CLIPV = 4.135166556742356f;  // log(1000/16)
constexpr float NEGV = -1e9f;

typedef unsigned long long ull;

__device__ __forceinline__ void decode_box(const float4& pr, const float4& rel,
                                           float Wf, float Hf,
                                           float& x1, float& y1, float& x2, float& y2) {
  float w = pr.z - pr.x, h = pr.w - pr.y;
  float cx = pr.x + 0.5f * w, cy = pr.y + 0.5f * h;
  float dx = rel.x / 10.0f, dy = rel.y / 10.0f;
  float dw = fminf(rel.z / 5.0f, CLIPV), dh = fminf(rel.w / 5.0f, CLIPV);
  float pcx = dx * w + cx, pcy = dy * h + cy;
  float pw = expf(dw) * w, ph = expf(dh) * h;
  x1 = fminf(fmaxf(pcx - 0.5f * pw, 0.0f), Wf);
  y1 = fminf(fmaxf(pcy - 0.5f * ph, 0.0f), Hf);
  x2 = fminf(fmaxf(pcx + 0.5f * pw, 0.0f), Wf);
  y2 = fminf(fmaxf(pcy + 0.5f * ph, 0.0f), Hf);
}

__device__ __forceinline__ int score_bucket(unsigned bits) {
  return min((int)((bits - 0x3D000000u) >> 14), NBUCK - 1);
}

__device__ __forceinline__ ull shfl64(ull v, int src) {
  int lo = __shfl((int)(unsigned)(v & 0xffffffffull), src, 64);
  int hi = __shfl((int)(unsigned)(v >> 32), src, 64);
  return ((ull)(unsigned)hi << 32) | (unsigned)lo;
}

__device__ __forceinline__ ull shfl_xor64(ull v, int d) {
  int lo = __shfl_xor((int)(unsigned)(v & 0xffffffffull), d, 64);
  int hi = __shfl_xor((int)(unsigned)(v >> 32), d, 64);
  return ((ull)(unsigned)hi << 32) | (unsigned)lo;
}

__global__ __launch_bounds__(256) void k_zero(int* ghist) {
  int g = blockIdx.x * 256 + threadIdx.x;
  if (g < NB * NBUCK) ghist[g] = 0;
}

// Thread-per-proposal with LDS staging: block of 128 threads stages 128x91
// logits coalesced (float4), then each thread does its own proposal's softmax
// serially (LDS stride 91 = 2-way bank alias = free). Logit-domain prefilter
// (strict superset, -1e-3 margin) gates the exact score test. Deterministic
// 24-slot output region per proposal: no contended atomics.
__global__ __launch_bounds__(PB) void k_candidates(
    const float* __restrict__ logits, const float* __restrict__ boxreg,
    const float* __restrict__ props, const int* __restrict__ hw,
    ull* __restrict__ keys, int* __restrict__ pcount, int* __restrict__ ghist) {
  __shared__ float sh[PB * NC];
  int tid = threadIdx.x;
  int base = blockIdx.x * PB;
  // stage PB*NC floats = 2912 float4 (block base is 16B-aligned: 128*91*4)
  const float4* src4 = reinterpret_cast<const float4*>(logits + (size_t)base * NC);
  float4* sh4 = reinterpret_cast<float4*>(sh);
  for (int i = tid; i < (PB * NC) / 4; i += PB) sh4[i] = src4[i];
  __syncthreads();

  int gw = base + tid;
  int b = gw >> 13;                    // NP = 8192
  int p = gw & (NP - 1);
  float Hf = (float)hw[0], Wf = (float)hw[1];
  const float* row = sh + tid * NC;

  float m = row[0];
#pragma unroll 7
  for (int j = 1; j < NC; ++j) m = fmaxf(m, row[j]);
  float S = 0.0f;
#pragma unroll 7
  for (int j = 0; j < NC; ++j) S += expf(row[j] - m);
  float invS = 1.0f / S;
  float thr = m + logf(SCORE_T * S) - 1e-3f;   // superset prefilter

  float4 pr = reinterpret_cast<const float4*>(props)[gw];
  const float4* relrow = reinterpret_cast<const float4*>(boxreg + (size_t)gw * 4 * NC);
  ull* krow = keys + (size_t)gw * SLOTS;
  int n = 0;
  for (int c = 1; c < NC; ++c) {
    float z = row[c];
    if (z > thr) {
      float sc = expf(z - m) * invS;
      if (sc > SCORE_T) {
        float4 rel = relrow[c];
        float x1, y1, x2, y2;
        decode_box(pr, rel, Wf, Hf, x1, y1, x2, y2);
        if (((x2 - x1) >= MIN_SZ) && ((y2 - y1) >= MIN_SZ)) {
          unsigned bits = __float_as_uint(sc);
          int idx = p * (NC - 1) + (c - 1);
          if (n < SLOTS) krow[n] = ((ull)bits << 32) | (unsigned)(~(unsigned)idx);
          ++n;
          atomicAdd(&ghist[b * NBUCK + score_bucket(bits)], 1);
        }
      }
    }
  }
  pcount[gw] = min(n, SLOTS);
}

// Per image: inclusive suffix scan of histogram -> threshold bucket, per-bucket
// output cursors (exclusive suffix offsets), and compact total.
__global__ __launch_bounds__(1024) void k_bound(
    const int* __restrict__ ghist, int* __restrict__ ccur,
    int* __restrict__ sboundA, int* __restrict__ ctotal) {
  __shared__ int h[NBUCK];
  __shared__ int sb;
  int b = blockIdx.x, tid = threadIdx.x;
#pragma unroll
  for (int k = 0; k < NBUCK / 1024; ++k) h[tid + k * 1024] = ghist[b * NBUCK + tid + k * 1024];
  if (tid == 0) sb = 0;
  __syncthreads();
  for (int d = 1; d < NBUCK; d <<= 1) {
    int v[NBUCK / 1024];
#pragma unroll
    for (int k = 0; k < NBUCK / 1024; ++k) {
      int i = tid + k * 1024;
      v[k] = h[i] + ((i + d < NBUCK) ? h[i + d] : 0);
    }
    __syncthreads();
#pragma unroll
    for (int k = 0; k < NBUCK / 1024; ++k) h[tid + k * 1024] = v[k];
    __syncthreads();
  }
#pragma unroll
  for (int k = 0; k < NBUCK / 1024; ++k) {
    int i = tid + k * 1024;
    if (h[i] >= KTOP && (i == NBUCK - 1 || h[i + 1] < KTOP)) sb = i;
  }
  __syncthreads();
#pragma unroll
  for (int k = 0; k < NBUCK / 1024; ++k) {
    int i = tid + k * 1024;
    ccur[b * NBUCK + i] = (i + 1 < NBUCK) ? h[i + 1] : 0;
  }
  if (tid == 0) {
    sboundA[b] = sb;
    ctotal[b] = h[sb];
  }
}

// Scatter passing candidates to per-bucket cursor positions (atomics spread
// over ~hundreds of bucket cursors; positions are globally unique in [0,total)).
__global__ __launch_bounds__(256) void k_compact(
    const ull* __restrict__ keys, const int* __restrict__ pcount,
    const int* __restrict__ sboundA, int* __restrict__ ccur,
    ull* __restrict__ ckeys) {
  int g = blockIdx.x * 256 + threadIdx.x;   // < NB*NP*SLOTS, grid exact
  int slot = g % SLOTS;
  int pp = g / SLOTS;
  int b = pp >> 13;                          // NP = 8192
  if (slot >= pcount[pp]) return;
  ull key = keys[g];
  int bk = score_bucket((unsigned)(key >> 32));
  if (bk < sboundA[b]) return;
  int pos = atomicAdd(&ccur[b * NBUCK + bk], 1);
  if (pos < SORTN) ckeys[(size_t)b * SORTN + pos] = key;
}

// Per-image bitonic sort of compacted keys (score desc, idx asc) -> top-1000.
__global__ __launch_bounds__(1024) void k_sort(
    const ull* __restrict__ ckeys, const int* __restrict__ ctotal,
    float* __restrict__ topk_score, int* __restrict__ topk_idx) {
  __shared__ ull skeys[SORTN];
  int b = blockIdx.x, tid = threadIdx.x;
  int total = min(ctotal[b], SORTN);
  for (int i = tid; i < SORTN; i += 1024)
    skeys[i] = (i < total) ? ckeys[(size_t)b * SORTN + i] : 0ull;
  __syncthreads();
  for (int k = 2; k <= SORTN; k <<= 1) {
    for (int j = k >> 1; j > 0; j >>= 1) {
      for (int t = tid; t < SORTN; t += 1024) {
        int ixj = t ^ j;
        if (ixj > t) {
          ull a = skeys[t], c2 = skeys[ixj];
          bool up = ((t & k) == 0);
          bool sw = up ? (a < c2) : (a > c2);
          if (sw) { skeys[t] = c2; skeys[ixj] = a; }
        }
      }
      __syncthreads();
    }
  }
  int valid_n = min(total, KTOP);
  if (tid < KTOP) {
    if (tid < valid_n) {
      ull key = skeys[tid];
      topk_score[b * KTOP + tid] = __uint_as_float((unsigned)(key >> 32));
      topk_idx[b * KTOP + tid] = (int)(~(unsigned)key);
    } else {
      topk_score[b * KTOP + tid] = NEGV;
      topk_idx[b * KTOP + tid] = -1;
    }
  }
}

__global__ __launch_bounds__(256) void k_decode(
    const float* __restrict__ boxreg, const float* __restrict__ props,
    const int* __restrict__ hw, const int* __restrict__ topk_idx,
    float* __restrict__ det_box, int* __restrict__ det_label,
    int* __restrict__ det_valid) {
  int g = blockIdx.x * 256 + threadIdx.x;
  if (g >= NB * KTOP) return;
  int b = g / KTOP;
  int fidx = topk_idx[g];
  if (fidx < 0) {
    det_box[(size_t)g * 4 + 0] = 0.0f;
    det_box[(size_t)g * 4 + 1] = 0.0f;
    det_box[(size_t)g * 4 + 2] = 0.0f;
    det_box[(size_t)g * 4 + 3] = 0.0f;
    det_label[g] = 0;
    det_valid[g] = 0;
    return;
  }
  int p = fidx / (NC - 1), c = fidx % (NC - 1) + 1;
  float Hf = (float)hw[0], Wf = (float)hw[1];
  float4 pr = reinterpret_cast<const float4*>(props)[b * NP + p];
  float4 rel =
      reinterpret_cast<const float4*>(boxreg + (size_t)(b * NP + p) * 4 * NC)[c];
  float x1, y1, x2, y2;
  decode_box(pr, rel, Wf, Hf, x1, y1, x2, y2);
  det_box[(size_t)g * 4 + 0] = x1;
  det_box[(size_t)g * 4 + 1] = y1;
  det_box[(size_t)g * 4 + 2] = x2;
  det_box[(size_t)g * 4 + 3] = y2;
  det_label[g] = c;
  det_valid[g] = 1;
}

// Suppression bit-matrix (labels-equal == class-offset NMS exactly, since
// offset_scale=1334 > max coord 1333 makes cross-class IoU 0).
__global__ __launch_bounds__(256) void k_mask(
    const float* __restrict__ det_box, const int* __restrict__ det_label,
    ull* __restrict__ maskmat) {
  int g = blockIdx.x * 256 + threadIdx.x;
  if (g >= NB * KTOP * 16) return;
  int w = g & 15;
  int i = (g >> 4) % KTOP;
  int b = (g >> 4) / KTOP;
  const float4* bb = reinterpret_cast<const float4*>(det_box) + (size_t)b * KTOP;
  const int* ll = det_label + b * KTOP;
  float4 bi = bb[i];
  int li = ll[i];
  float areai = (bi.z - bi.x) * (bi.w - bi.y);
  ull bits = 0;
  int j0 = w * 64;
  for (int t = 0; t < 64; ++t) {
    int j = j0 + t;
    if (j > i && j < KTOP && ll[j] == li) {
      float4 bj = bb[j];
      float areaj = (bj.z - bj.x) * (bj.w - bj.y);
      float ltx = fmaxf(bi.x, bj.x), lty = fmaxf(bi.y, bj.y);
      float rbx = fminf(bi.z, bj.z), rby = fminf(bi.w, bj.w);
      float iw = fmaxf(rbx - ltx, 0.0f), ih = fmaxf(rby - lty, 0.0f);
      float inter = iw * ih;
      float iou = inter / (areai + areaj - inter + 1e-9f);
      if (iou > NMS_T) bits |= (1ull << t);
    }
  }
  maskmat[((size_t)b * MROWS + i) * 16 + w] = bits;
}

// Windowed greedy NMS: 16 windows of 64 rows. Per window: transpose the 64x64
// intra block across lanes (6 shfl_xor stages), resolve 64 decisions with a
// register-only ballot loop, then OR kept rows' masks into 4-way-partial supp
// (all 64 lanes: group g = lane>>4 handles 16 rows, word = lane&15).
__global__ __launch_bounds__(64) void k_greedy(
    const ull* __restrict__ maskmat, const int* __restrict__ det_valid,
    int* __restrict__ keep) {
  int b = blockIdx.x;
  int lane = threadIdx.x;
  int wl = lane & 15;
  int grp = lane >> 4;
  ull validw = 0;
#pragma unroll
  for (int w = 0; w < 16; ++w) {
    int j = w * 64 + lane;
    int f = (j < KTOP) ? det_valid[b * KTOP + j] : 0;
    ull m = __ballot(f != 0);
    if (lane == w) validw = m;
  }
  ull supp = (lane < 16) ? ~validw : 0ull;  // invalid == pre-suppressed
  const ull* mrow = maskmat + (size_t)b * MROWS * 16;

  for (int w = 0; w < 16; ++w) {
    int t0 = w * 64;
    int row = t0 + lane;
    ull r = mrow[(size_t)row * 16 + w];
    if (row >= KTOP) r = 0ull;
#pragma unroll
    for (int dd = 0; dd < 6; ++dd) {
      const int d = 1 << dd;
      const ull M0 = (dd == 0) ? 0x5555555555555555ull
                   : (dd == 1) ? 0x3333333333333333ull
                   : (dd == 2) ? 0x0F0F0F0F0F0F0F0Full
                   : (dd == 3) ? 0x00FF00FF00FF00FFull
                   : (dd == 4) ? 0x0000FFFF0000FFFFull
                               : 0x00000000FFFFFFFFull;
      ull y = shfl_xor64(r, d);
      r = ((lane & d) == 0) ? ((r & M0) | ((y & M0) << d))
                            : ((r & ~M0) | ((y >> d) & M0));
    }
    ull inc = shfl64(supp, w) | shfl64(supp, w + 16) |
              shfl64(supp, w + 32) | shfl64(supp, w + 48);
    unsigned s32 = (unsigned)((inc >> lane) & 1ull);
#pragma unroll
    for (int i = 0; i < 64; ++i) {
      ull act = __ballot(s32 == 0);
      s32 |= (unsigned)(((act & r) >> i) & 1ull);
    }
    ull K = __ballot(s32 == 0);
    if (row < KTOP) keep[b * KTOP + row] = (s32 == 0) ? 1 : 0;
    ull acc = 0;
    int base_r = grp * 16;
#pragma unroll
    for (int k = 0; k < 16; ++k) {
      int i = base_r + k;
      ull v = mrow[(size_t)(t0 + i) * 16 + wl];
      if ((K >> i) & 1ull) acc |= v;
    }
    supp |= acc;
  }
}

// First 100 kept (in sorted order) -> outputs, zero-pad the rest.
__global__ __launch_bounds__(256) void k_output(
    const float* __restrict__ topk_score, const float* __restrict__ det_box,
    const int* __restrict__ det_label, const int* __restrict__ keep,
    float* __restrict__ out) {
  int b = blockIdx.x, tid = threadIdx.x;
  __shared__ int pf[1024];
  for (int i = tid; i < 1024; i += 256) pf[i] = (i < KTOP) ? keep[b * KTOP + i] : 0;
  __syncthreads();
  for (int d = 1; d < 1024; d <<= 1) {
    int v[4];
#pragma unroll
    for (int k = 0; k < 4; ++k) {
      int i = tid + k * 256;
      v[k] = pf[i] + ((i >= d) ? pf[i - d] : 0);
    }
    __syncthreads();
#pragma unroll
    for (int k = 0; k < 4; ++k) pf[tid + k * 256] = v[k];
    __syncthreads();
  }
  int total = min(pf[KTOP - 1], NDET);
  float* ob = out;
  float* os = out + (size_t)NB * NDET * 4;
  float* ol = os + (size_t)NB * NDET;
  for (int i = tid; i < KTOP; i += 256) {
    if (keep[b * KTOP + i]) {
      int r = pf[i] - 1;
      if (r < NDET) {
        ob[((size_t)b * NDET + r) * 4 + 0] = det_box[((size_t)b * KTOP + i) * 4 + 0];
        ob[((size_t)b * NDET + r) * 4 + 1] = det_box[((size_t)b * KTOP + i) * 4 + 1];
        ob[((size_t)b * NDET + r) * 4 + 2] = det_box[((size_t)b * KTOP + i) * 4 + 2];
        ob[((size_t)b * NDET + r) * 4 + 3] = det_box[((size_t)b * KTOP + i) * 4 + 3];
        os[b * NDET + r] = topk_score[b * KTOP + i];
        ol[b * NDET + r] = (float)det_label[b * KTOP + i];
      }
    }
  }
  for (int r = total + tid; r < NDET; r += 256) {
    ob[((size_t)b * NDET + r) * 4 + 0] = 0.0f;
    ob[((size_t)b * NDET + r) * 4 + 1] = 0.0f;
    ob[((size_t)b * NDET + r) * 4 + 2] = 0.0f;
    ob[((size_t)b * NDET + r) * 4 + 3] = 0.0f;
    os[b * NDET + r] = 0.0f;
    ol[b * NDET + r] = 0.0f;
  }
}

}  // namespace

extern "C" void kernel_launch(void* const* d_in, const int* in_sizes, int n_in,
                              void* d_out, int out_size, void* d_ws, size_t ws_size,
                              hipStream_t stream) {
  const float* logits = (const float*)d_in[0];
  const float* boxreg = (const float*)d_in[1];
  const float* props = (const float*)d_in[2];
  const int* hw = (const int*)d_in[3];

  char* ws = (char*)d_ws;
  size_t off = 0;
  auto alloc = [&](size_t bytes) -> void* {
    void* p = ws + off;
    off += (bytes + 255) & ~(size_t)255;
    return p;
  };
  ull* keys = (ull*)alloc((size_t)NB * NP * SLOTS * 8);
  int* pcount = (int*)alloc((size_t)NB * NP * 4);
  int* ghist = (int*)alloc((size_t)NB * NBUCK * 4);
  int* ccur = (int*)alloc((size_t)NB * NBUCK * 4);
  int* sboundA = (int*)alloc(NB * 4);
  int* ctotal = (int*)alloc(NB * 4);
  ull* ckeys = (ull*)alloc((size_t)NB * SORTN * 8);
  float* topk_score = (float*)alloc((size_t)NB * KTOP * 4);
  int* topk_idx = (int*)alloc((size_t)NB * KTOP * 4);
  float* det_box = (float*)alloc((size_t)NB * KTOP * 16);
  int* det_label = (int*)alloc((size_t)NB * KTOP * 4);
  int* det_valid = (int*)alloc((size_t)NB * KTOP * 4);
  ull* maskmat = (ull*)alloc((size_t)NB * MROWS * 16 * 8);
  int* keep = (int*)alloc((size_t)NB * KTOP * 4);

  k_zero<<<(NB * NBUCK + 255) / 256, 256, 0, stream>>>(ghist);
  k_candidates<<<(NB * NP) / PB, PB, 0, stream>>>(logits, boxreg, props, hw,
                                                  keys, pcount, ghist);
  k_bound<<<NB, 1024, 0, stream>>>(ghist, ccur, sboundA, ctotal);
  k_compact<<<(NB * NP * SLOTS) / 256, 256, 0, stream>>>(keys, pcount, sboundA, ccur, ckeys);
  k_sort<<<NB, 1024, 0, stream>>>(ckeys, ctotal, topk_score, topk_idx);
  k_decode<<<(NB * KTOP + 255) / 256, 256, 0, stream>>>(boxreg, props, hw, topk_idx,
                                                        det_box, det_label, det_valid);
  k_mask<<<(NB * KTOP * 16 + 255) / 256, 256, 0, stream>>>(det_box, det_label, maskmat);
  k_greedy<<<NB, 64, 0, stream>>>(maskmat, det_valid, keep);
  k_output<<<NB, 256, 0, stream>>>(topk_score, det_box, det_label, keep, (float*)d_out);
}

// Round 6
// 198.461 us; speedup vs baseline: 1.1436x; 1.1436x over previous
//
#include <hip/hip_runtime.h>

namespace {

constexpr int NB = 8, NP = 8192, NC = 91;
constexpr int KTOP = 1000, NDET = 100;
constexpr int MROWS = 1024;          // padded mask rows per image (16 windows of 64)
constexpr int SLOTS = 24;            // max candidates/proposal: scores sum<=1 => <=19 can be >0.05
constexpr int NBUCK = 4096, SORTN = 4096;
constexpr float SCORE_T = 0.05f;
constexpr float MIN_SZ = 0.01f;
constexpr float NMS_T = 0.5f;
constexpr float CLIPV = 4.135166556742356f;  // log(1000/16)
constexpr float NEGV = -1e9f;

typedef unsigned long long ull;

__device__ __forceinline__ void decode_box(const float4& pr, const float4& rel,
                                           float Wf, float Hf,
                                           float& x1, float& y1, float& x2, float& y2) {
  float w = pr.z - pr.x, h = pr.w - pr.y;
  float cx = pr.x + 0.5f * w, cy = pr.y + 0.5f * h;
  float dx = rel.x / 10.0f, dy = rel.y / 10.0f;
  float dw = fminf(rel.z / 5.0f, CLIPV), dh = fminf(rel.w / 5.0f, CLIPV);
  float pcx = dx * w + cx, pcy = dy * h + cy;
  float pw = expf(dw) * w, ph = expf(dh) * h;
  x1 = fminf(fmaxf(pcx - 0.5f * pw, 0.0f), Wf);
  y1 = fminf(fmaxf(pcy - 0.5f * ph, 0.0f), Hf);
  x2 = fminf(fmaxf(pcx + 0.5f * pw, 0.0f), Wf);
  y2 = fminf(fmaxf(pcy + 0.5f * ph, 0.0f), Hf);
}

__device__ __forceinline__ int score_bucket(unsigned bits) {
  return min((int)((bits - 0x3D000000u) >> 14), NBUCK - 1);
}

__device__ __forceinline__ ull shfl64(ull v, int src) {
  int lo = __shfl((int)(unsigned)(v & 0xffffffffull), src, 64);
  int hi = __shfl((int)(unsigned)(v >> 32), src, 64);
  return ((ull)(unsigned)hi << 32) | (unsigned)lo;
}

__device__ __forceinline__ ull shfl_xor64(ull v, int d) {
  int lo = __shfl_xor((int)(unsigned)(v & 0xffffffffull), d, 64);
  int hi = __shfl_xor((int)(unsigned)(v >> 32), d, 64);
  return ((ull)(unsigned)hi << 32) | (unsigned)lo;
}

__global__ __launch_bounds__(256) void k_zero(int* ghist) {
  int g = blockIdx.x * 256 + threadIdx.x;
  if (g < NB * NBUCK) ghist[g] = 0;
}

// 16-lane group per proposal (4 proposals/wave, no LDS): 6 coalesced strip
// loads keep the row in registers (zreg[6]); 4-stage group shfl reductions for
// max and sum; candidate pass reuses zreg with logit-domain prefilter (strict
// superset, -1e-3 margin) before the exact score test. Deterministic 24-slot
// output region per proposal: no contended atomics.
__global__ __launch_bounds__(256) void k_candidates(
    const float* __restrict__ logits, const float* __restrict__ boxreg,
    const float* __restrict__ props, const int* __restrict__ hw,
    ull* __restrict__ keys, int* __restrict__ pcount, int* __restrict__ ghist) {
  int tid = threadIdx.x;
  int lane = tid & 63;
  int l16 = lane & 15;
  int grp = lane >> 4;
  int wv = tid >> 6;
  int gw = blockIdx.x * 16 + wv * 4 + grp;   // proposal; grid exact, image-uniform per block
  int b = gw >> 13;                           // NP = 8192
  int p = gw & (NP - 1);
  float Hf = (float)hw[0], Wf = (float)hw[1];
  const float* lrow = logits + (size_t)gw * NC;

  float zreg[6];
  float m = -3.0e38f;
#pragma unroll
  for (int k = 0; k < 6; ++k) {
    int c = k * 16 + l16;
    float z = (c < NC) ? lrow[c] : -3.0e38f;
    zreg[k] = z;
    m = fmaxf(m, z);
  }
#pragma unroll
  for (int d = 1; d < 16; d <<= 1) m = fmaxf(m, __shfl_xor(m, d, 64));
  float S = 0.0f;
#pragma unroll
  for (int k = 0; k < 6; ++k) {
    int c = k * 16 + l16;
    S += (c < NC) ? expf(zreg[k] - m) : 0.0f;
  }
#pragma unroll
  for (int d = 1; d < 16; d <<= 1) S += __shfl_xor(S, d, 64);

  float invS = 1.0f / S;
  float thr = m + logf(SCORE_T * S) - 1e-3f;   // superset prefilter

  float4 pr = reinterpret_cast<const float4*>(props)[gw];
  const float4* relrow = reinterpret_cast<const float4*>(boxreg + (size_t)gw * 4 * NC);
  ull* krow = keys + (size_t)gw * SLOTS;
  unsigned below = (1u << l16) - 1u;
  int n = 0;
#pragma unroll
  for (int k = 0; k < 6; ++k) {
    int c = k * 16 + l16;
    bool ok = (c >= 1) && (c < NC) && (zreg[k] > thr);
    float sc = 0.0f;
    if (ok) {
      sc = expf(zreg[k] - m) * invS;
      ok = sc > SCORE_T;
      if (ok) {
        float4 rel = relrow[c];
        float x1, y1, x2, y2;
        decode_box(pr, rel, Wf, Hf, x1, y1, x2, y2);
        ok = ((x2 - x1) >= MIN_SZ) && ((y2 - y1) >= MIN_SZ);
      }
    }
    ull bal = __ballot(ok);
    unsigned gm = (unsigned)((bal >> (grp * 16)) & 0xFFFFull);
    if (ok) {
      int pos = n + __popc(gm & below);
      unsigned bits = __float_as_uint(sc);
      int idx = p * (NC - 1) + (c - 1);
      if (pos < SLOTS) krow[pos] = ((ull)bits << 32) | (unsigned)(~(unsigned)idx);
      atomicAdd(&ghist[b * NBUCK + score_bucket(bits)], 1);
    }
    n += __popc(gm);
  }
  if (l16 == 0) pcount[gw] = min(n, SLOTS);
}

// Per image: inclusive suffix scan of histogram -> threshold bucket, per-bucket
// output cursors (exclusive suffix offsets), and compact total.
__global__ __launch_bounds__(1024) void k_bound(
    const int* __restrict__ ghist, int* __restrict__ ccur,
    int* __restrict__ sboundA, int* __restrict__ ctotal) {
  __shared__ int h[NBUCK];
  __shared__ int sb;
  int b = blockIdx.x, tid = threadIdx.x;
#pragma unroll
  for (int k = 0; k < NBUCK / 1024; ++k) h[tid + k * 1024] = ghist[b * NBUCK + tid + k * 1024];
  if (tid == 0) sb = 0;
  __syncthreads();
  for (int d = 1; d < NBUCK; d <<= 1) {
    int v[NBUCK / 1024];
#pragma unroll
    for (int k = 0; k < NBUCK / 1024; ++k) {
      int i = tid + k * 1024;
      v[k] = h[i] + ((i + d < NBUCK) ? h[i + d] : 0);
    }
    __syncthreads();
#pragma unroll
    for (int k = 0; k < NBUCK / 1024; ++k) h[tid + k * 1024] = v[k];
    __syncthreads();
  }
#pragma unroll
  for (int k = 0; k < NBUCK / 1024; ++k) {
    int i = tid + k * 1024;
    if (h[i] >= KTOP && (i == NBUCK - 1 || h[i + 1] < KTOP)) sb = i;
  }
  __syncthreads();
#pragma unroll
  for (int k = 0; k < NBUCK / 1024; ++k) {
    int i = tid + k * 1024;
    ccur[b * NBUCK + i] = (i + 1 < NBUCK) ? h[i + 1] : 0;
  }
  if (tid == 0) {
    sboundA[b] = sb;
    ctotal[b] = h[sb];
  }
}

// Scatter passing candidates to per-bucket cursor positions (atomics spread
// over ~hundreds of bucket cursors; positions are globally unique in [0,total)).
__global__ __launch_bounds__(256) void k_compact(
    const ull* __restrict__ keys, const int* __restrict__ pcount,
    const int* __restrict__ sboundA, int* __restrict__ ccur,
    ull* __restrict__ ckeys) {
  int g = blockIdx.x * 256 + threadIdx.x;   // < NB*NP*SLOTS, grid exact
  int slot = g % SLOTS;
  int pp = g / SLOTS;
  int b = pp >> 13;                          // NP = 8192
  if (slot >= pcount[pp]) return;
  ull key = keys[g];
  int bk = score_bucket((unsigned)(key >> 32));
  if (bk < sboundA[b]) return;
  int pos = atomicAdd(&ccur[b * NBUCK + bk], 1);
  if (pos < SORTN) ckeys[(size_t)b * SORTN + pos] = key;
}

// Per-image bitonic sort of compacted keys (score desc, idx asc) -> top-1000.
__global__ __launch_bounds__(1024) void k_sort(
    const ull* __restrict__ ckeys, const int* __restrict__ ctotal,
    float* __restrict__ topk_score, int* __restrict__ topk_idx) {
  __shared__ ull skeys[SORTN];
  int b = blockIdx.x, tid = threadIdx.x;
  int total = min(ctotal[b], SORTN);
  for (int i = tid; i < SORTN; i += 1024)
    skeys[i] = (i < total) ? ckeys[(size_t)b * SORTN + i] : 0ull;
  __syncthreads();
  for (int k = 2; k <= SORTN; k <<= 1) {
    for (int j = k >> 1; j > 0; j >>= 1) {
      for (int t = tid; t < SORTN; t += 1024) {
        int ixj = t ^ j;
        if (ixj > t) {
          ull a = skeys[t], c2 = skeys[ixj];
          bool up = ((t & k) == 0);
          bool sw = up ? (a < c2) : (a > c2);
          if (sw) { skeys[t] = c2; skeys[ixj] = a; }
        }
      }
      __syncthreads();
    }
  }
  int valid_n = min(total, KTOP);
  if (tid < KTOP) {
    if (tid < valid_n) {
      ull key = skeys[tid];
      topk_score[b * KTOP + tid] = __uint_as_float((unsigned)(key >> 32));
      topk_idx[b * KTOP + tid] = (int)(~(unsigned)key);
    } else {
      topk_score[b * KTOP + tid] = NEGV;
      topk_idx[b * KTOP + tid] = -1;
    }
  }
}

__global__ __launch_bounds__(256) void k_decode(
    const float* __restrict__ boxreg, const float* __restrict__ props,
    const int* __restrict__ hw, const int* __restrict__ topk_idx,
    float* __restrict__ det_box, int* __restrict__ det_label,
    int* __restrict__ det_valid) {
  int g = blockIdx.x * 256 + threadIdx.x;
  if (g >= NB * KTOP) return;
  int b = g / KTOP;
  int fidx = topk_idx[g];
  if (fidx < 0) {
    det_box[(size_t)g * 4 + 0] = 0.0f;
    det_box[(size_t)g * 4 + 1] = 0.0f;
    det_box[(size_t)g * 4 + 2] = 0.0f;
    det_box[(size_t)g * 4 + 3] = 0.0f;
    det_label[g] = 0;
    det_valid[g] = 0;
    return;
  }
  int p = fidx / (NC - 1), c = fidx % (NC - 1) + 1;
  float Hf = (float)hw[0], Wf = (float)hw[1];
  float4 pr = reinterpret_cast<const float4*>(props)[b * NP + p];
  float4 rel =
      reinterpret_cast<const float4*>(boxreg + (size_t)(b * NP + p) * 4 * NC)[c];
  float x1, y1, x2, y2;
  decode_box(pr, rel, Wf, Hf, x1, y1, x2, y2);
  det_box[(size_t)g * 4 + 0] = x1;
  det_box[(size_t)g * 4 + 1] = y1;
  det_box[(size_t)g * 4 + 2] = x2;
  det_box[(size_t)g * 4 + 3] = y2;
  det_label[g] = c;
  det_valid[g] = 1;
}

// Suppression bit-matrix (labels-equal == class-offset NMS exactly, since
// offset_scale=1334 > max coord 1333 makes cross-class IoU 0).
__global__ __launch_bounds__(256) void k_mask(
    const float* __restrict__ det_box, const int* __restrict__ det_label,
    ull* __restrict__ maskmat) {
  int g = blockIdx.x * 256 + threadIdx.x;
  if (g >= NB * KTOP * 16) return;
  int w = g & 15;
  int i = (g >> 4) % KTOP;
  int b = (g >> 4) / KTOP;
  const float4* bb = reinterpret_cast<const float4*>(det_box) + (size_t)b * KTOP;
  const int* ll = det_label + b * KTOP;
  float4 bi = bb[i];
  int li = ll[i];
  float areai = (bi.z - bi.x) * (bi.w - bi.y);
  ull bits = 0;
  int j0 = w * 64;
  for (int t = 0; t < 64; ++t) {
    int j = j0 + t;
    if (j > i && j < KTOP && ll[j] == li) {
      float4 bj = bb[j];
      float areaj = (bj.z - bj.x) * (bj.w - bj.y);
      float ltx = fmaxf(bi.x, bj.x), lty = fmaxf(bi.y, bj.y);
      float rbx = fminf(bi.z, bj.z), rby = fminf(bi.w, bj.w);
      float iw = fmaxf(rbx - ltx, 0.0f), ih = fmaxf(rby - lty, 0.0f);
      float inter = iw * ih;
      float iou = inter / (areai + areaj - inter + 1e-9f);
      if (iou > NMS_T) bits |= (1ull << t);
    }
  }
  maskmat[((size_t)b * MROWS + i) * 16 + w] = bits;
}

// Windowed greedy NMS: 16 windows of 64 rows. Per window: transpose the 64x64
// intra block across lanes (6 shfl_xor stages), resolve 64 decisions with a
// register-only ballot loop, then OR kept rows' masks into 4-way-partial supp
// (all 64 lanes: group g = lane>>4 handles 16 rows, word = lane&15).
__global__ __launch_bounds__(64) void k_greedy(
    const ull* __restrict__ maskmat, const int* __restrict__ det_valid,
    int* __restrict__ keep) {
  int b = blockIdx.x;
  int lane = threadIdx.x;
  int wl = lane & 15;
  int grp = lane >> 4;
  ull validw = 0;
#pragma unroll
  for (int w = 0; w < 16; ++w) {
    int j = w * 64 + lane;
    int f = (j < KTOP) ? det_valid[b * KTOP + j] : 0;
    ull m = __ballot(f != 0);
    if (lane == w) validw = m;
  }
  ull supp = (lane < 16) ? ~validw : 0ull;  // invalid == pre-suppressed
  const ull* mrow = maskmat + (size_t)b * MROWS * 16;

  for (int w = 0; w < 16; ++w) {
    int t0 = w * 64;
    int row = t0 + lane;
    ull r = mrow[(size_t)row * 16 + w];
    if (row >= KTOP) r = 0ull;
#pragma unroll
    for (int dd = 0; dd < 6; ++dd) {
      const int d = 1 << dd;
      const ull M0 = (dd == 0) ? 0x5555555555555555ull
                   : (dd == 1) ? 0x3333333333333333ull
                   : (dd == 2) ? 0x0F0F0F0F0F0F0F0Full
                   : (dd == 3) ? 0x00FF00FF00FF00FFull
                   : (dd == 4) ? 0x0000FFFF0000FFFFull
                               : 0x00000000FFFFFFFFull;
      ull y = shfl_xor64(r, d);
      r = ((lane & d) == 0) ? ((r & M0) | ((y & M0) << d))
                            : ((r & ~M0) | ((y >> d) & M0));
    }
    ull inc = shfl64(supp, w) | shfl64(supp, w + 16) |
              shfl64(supp, w + 32) | shfl64(supp, w + 48);
    unsigned s32 = (unsigned)((inc >> lane) & 1ull);
#pragma unroll
    for (int i = 0; i < 64; ++i) {
      ull act = __ballot(s32 == 0);
      s32 |= (unsigned)(((act & r) >> i) & 1ull);
    }
    ull K = __ballot(s32 == 0);
    if (row < KTOP) keep[b * KTOP + row] = (s32 == 0) ? 1 : 0;
    ull acc = 0;
    int base_r = grp * 16;
#pragma unroll
    for (int k = 0; k < 16; ++k) {
      int i = base_r + k;
      ull v = mrow[(size_t)(t0 + i) * 16 + wl];
      if ((K >> i) & 1ull) acc |= v;
    }
    supp |= acc;
  }
}

// First 100 kept (in sorted order) -> outputs, zero-pad the rest.
__global__ __launch_bounds__(256) void k_output(
    const float* __restrict__ topk_score, const float* __restrict__ det_box,
    const int* __restrict__ det_label, const int* __restrict__ keep,
    float* __restrict__ out) {
  int b = blockIdx.x, tid = threadIdx.x;
  __shared__ int pf[1024];
  for (int i = tid; i < 1024; i += 256) pf[i] = (i < KTOP) ? keep[b * KTOP + i] : 0;
  __syncthreads();
  for (int d = 1; d < 1024; d <<= 1) {
    int v[4];
#pragma unroll
    for (int k = 0; k < 4; ++k) {
      int i = tid + k * 256;
      v[k] = pf[i] + ((i >= d) ? pf[i - d] : 0);
    }
    __syncthreads();
#pragma unroll
    for (int k = 0; k < 4; ++k) pf[tid + k * 256] = v[k];
    __syncthreads();
  }
  int total = min(pf[KTOP - 1], NDET);
  float* ob = out;
  float* os = out + (size_t)NB * NDET * 4;
  float* ol = os + (size_t)NB * NDET;
  for (int i = tid; i < KTOP; i += 256) {
    if (keep[b * KTOP + i]) {
      int r = pf[i] - 1;
      if (r < NDET) {
        ob[((size_t)b * NDET + r) * 4 + 0] = det_box[((size_t)b * KTOP + i) * 4 + 0];
        ob[((size_t)b * NDET + r) * 4 + 1] = det_box[((size_t)b * KTOP + i) * 4 + 1];
        ob[((size_t)b * NDET + r) * 4 + 2] = det_box[((size_t)b * KTOP + i) * 4 + 2];
        ob[((size_t)b * NDET + r) * 4 + 3] = det_box[((size_t)b * KTOP + i) * 4 + 3];
        os[b * NDET + r] = topk_score[b * KTOP + i];
        ol[b * NDET + r] = (float)det_label[b * KTOP + i];
      }
    }
  }
  for (int r = total + tid; r < NDET; r += 256) {
    ob[((size_t)b * NDET + r) * 4 + 0] = 0.0f;
    ob[((size_t)b * NDET + r) * 4 + 1] = 0.0f;
    ob[((size_t)b * NDET + r) * 4 + 2] = 0.0f;
    ob[((size_t)b * NDET + r) * 4 + 3] = 0.0f;
    os[b * NDET + r] = 0.0f;
    ol[b * NDET + r] = 0.0f;
  }
}

}  // namespace

extern "C" void kernel_launch(void* const* d_in, const int* in_sizes, int n_in,
                              void* d_out, int out_size, void* d_ws, size_t ws_size,
                              hipStream_t stream) {
  const float* logits = (const float*)d_in[0];
  const float* boxreg = (const float*)d_in[1];
  const float* props = (const float*)d_in[2];
  const int* hw = (const int*)d_in[3];

  char* ws = (char*)d_ws;
  size_t off = 0;
  auto alloc = [&](size_t bytes) -> void* {
    void* p = ws + off;
    off += (bytes + 255) & ~(size_t)255;
    return p;
  };
  ull* keys = (ull*)alloc((size_t)NB * NP * SLOTS * 8);
  int* pcount = (int*)alloc((size_t)NB * NP * 4);
  int* ghist = (int*)alloc((size_t)NB * NBUCK * 4);
  int* ccur = (int*)alloc((size_t)NB * NBUCK * 4);
  int* sboundA = (int*)alloc(NB * 4);
  int* ctotal = (int*)alloc(NB * 4);
  ull* ckeys = (ull*)alloc((size_t)NB * SORTN * 8);
  float* topk_score = (float*)alloc((size_t)NB * KTOP * 4);
  int* topk_idx = (int*)alloc((size_t)NB * KTOP * 4);
  float* det_box = (float*)alloc((size_t)NB * KTOP * 16);
  int* det_label = (int*)alloc((size_t)NB * KTOP * 4);
  int* det_valid = (int*)alloc((size_t)NB * KTOP * 4);
  ull* maskmat = (ull*)alloc((size_t)NB * MROWS * 16 * 8);
  int* keep = (int*)alloc((size_t)NB * KTOP * 4);

  k_zero<<<(NB * NBUCK + 255) / 256, 256, 0, stream>>>(ghist);
  k_candidates<<<(NB * NP) / 16, 256, 0, stream>>>(logits, boxreg, props, hw,
                                                   keys, pcount, ghist);
  k_bound<<<NB, 1024, 0, stream>>>(ghist, ccur, sboundA, ctotal);
  k_compact<<<(NB * NP * SLOTS) / 256, 256, 0, stream>>>(keys, pcount, sboundA, ccur, ckeys);
  k_sort<<<NB, 1024, 0, stream>>>(ckeys, ctotal, topk_score, topk_idx);
  k_decode<<<(NB * KTOP + 255) / 256, 256, 0, stream>>>(boxreg, props, hw, topk_idx,
                                                        det_box, det_label, det_valid);
  k_mask<<<(NB * KTOP * 16 + 255) / 256, 256, 0, stream>>>(det_box, det_label, maskmat);
  k_greedy<<<NB, 64, 0, stream>>>(maskmat, det_valid, keep);
  k_output<<<NB, 256, 0, stream>>>(topk_score, det_box, det_label, keep, (float*)d_out);
}

// Round 7
// 150.976 us; speedup vs baseline: 1.5033x; 1.3145x over previous
//
#include <hip/hip_runtime.h>

namespace {

constexpr int NB = 8, NP = 8192, NC = 91;
constexpr int KTOP = 1000, NDET = 100;
constexpr int MROWS = 1024;          // padded mask rows per image (16 windows of 64)
constexpr int SLOTS = 24;            // max candidates/proposal: scores sum<=1 => <=19 can be >0.05
constexpr int NBUCK = 4096, SORTN = 4096;
constexpr float SCORE_T = 0.05f;
constexpr float MIN_SZ = 0.01f;
constexpr float NMS_T = 0.5f;
constexpr float CLIPV = 4.135166556742356f;  // log(1000/16)
constexpr float NEGV = -1e9f;

typedef unsigned long long ull;

__device__ __forceinline__ void decode_box(const float4& pr, const float4& rel,
                                           float Wf, float Hf,
                                           float& x1, float& y1, float& x2, float& y2) {
  float w = pr.z - pr.x, h = pr.w - pr.y;
  float cx = pr.x + 0.5f * w, cy = pr.y + 0.5f * h;
  float dx = rel.x / 10.0f, dy = rel.y / 10.0f;
  float dw = fminf(rel.z / 5.0f, CLIPV), dh = fminf(rel.w / 5.0f, CLIPV);
  float pcx = dx * w + cx, pcy = dy * h + cy;
  float pw = expf(dw) * w, ph = expf(dh) * h;
  x1 = fminf(fmaxf(pcx - 0.5f * pw, 0.0f), Wf);
  y1 = fminf(fmaxf(pcy - 0.5f * ph, 0.0f), Hf);
  x2 = fminf(fmaxf(pcx + 0.5f * pw, 0.0f), Wf);
  y2 = fminf(fmaxf(pcy + 0.5f * ph, 0.0f), Hf);
}

__device__ __forceinline__ int score_bucket(unsigned bits) {
  return min((int)((bits - 0x3D000000u) >> 14), NBUCK - 1);
}

__device__ __forceinline__ ull shfl64(ull v, int src) {
  int lo = __shfl((int)(unsigned)(v & 0xffffffffull), src, 64);
  int hi = __shfl((int)(unsigned)(v >> 32), src, 64);
  return ((ull)(unsigned)hi << 32) | (unsigned)lo;
}

__device__ __forceinline__ ull shfl_xor64(ull v, int d) {
  int lo = __shfl_xor((int)(unsigned)(v & 0xffffffffull), d, 64);
  int hi = __shfl_xor((int)(unsigned)(v >> 32), d, 64);
  return ((ull)(unsigned)hi << 32) | (unsigned)lo;
}

__global__ __launch_bounds__(256) void k_zero(int* ghist) {
  int g = blockIdx.x * 256 + threadIdx.x;
  if (g < NB * NBUCK) ghist[g] = 0;
}

// 16-lane group per proposal (4 proposals/wave, no LDS): 6 coalesced strip
// loads keep the row in registers (zreg[6]); 4-stage group shfl reductions for
// max and sum; candidate pass reuses zreg with logit-domain prefilter (strict
// superset, -1e-3 margin) before the exact score test. Deterministic 24-slot
// output region per proposal: no contended atomics.
__global__ __launch_bounds__(256) void k_candidates(
    const float* __restrict__ logits, const float* __restrict__ boxreg,
    const float* __restrict__ props, const int* __restrict__ hw,
    ull* __restrict__ keys, int* __restrict__ pcount, int* __restrict__ ghist) {
  int tid = threadIdx.x;
  int lane = tid & 63;
  int l16 = lane & 15;
  int grp = lane >> 4;
  int wv = tid >> 6;
  int gw = blockIdx.x * 16 + wv * 4 + grp;   // proposal; grid exact, image-uniform per block
  int b = gw >> 13;                           // NP = 8192
  int p = gw & (NP - 1);
  float Hf = (float)hw[0], Wf = (float)hw[1];
  const float* lrow = logits + (size_t)gw * NC;

  float zreg[6];
  float m = -3.0e38f;
#pragma unroll
  for (int k = 0; k < 6; ++k) {
    int c = k * 16 + l16;
    float z = (c < NC) ? lrow[c] : -3.0e38f;
    zreg[k] = z;
    m = fmaxf(m, z);
  }
#pragma unroll
  for (int d = 1; d < 16; d <<= 1) m = fmaxf(m, __shfl_xor(m, d, 64));
  float S = 0.0f;
#pragma unroll
  for (int k = 0; k < 6; ++k) {
    int c = k * 16 + l16;
    S += (c < NC) ? expf(zreg[k] - m) : 0.0f;
  }
#pragma unroll
  for (int d = 1; d < 16; d <<= 1) S += __shfl_xor(S, d, 64);

  float invS = 1.0f / S;
  float thr = m + logf(SCORE_T * S) - 1e-3f;   // superset prefilter

  float4 pr = reinterpret_cast<const float4*>(props)[gw];
  const float4* relrow = reinterpret_cast<const float4*>(boxreg + (size_t)gw * 4 * NC);
  ull* krow = keys + (size_t)gw * SLOTS;
  unsigned below = (1u << l16) - 1u;
  int n = 0;
#pragma unroll
  for (int k = 0; k < 6; ++k) {
    int c = k * 16 + l16;
    bool ok = (c >= 1) && (c < NC) && (zreg[k] > thr);
    float sc = 0.0f;
    if (ok) {
      sc = expf(zreg[k] - m) * invS;
      ok = sc > SCORE_T;
      if (ok) {
        float4 rel = relrow[c];
        float x1, y1, x2, y2;
        decode_box(pr, rel, Wf, Hf, x1, y1, x2, y2);
        ok = ((x2 - x1) >= MIN_SZ) && ((y2 - y1) >= MIN_SZ);
      }
    }
    ull bal = __ballot(ok);
    unsigned gm = (unsigned)((bal >> (grp * 16)) & 0xFFFFull);
    if (ok) {
      int pos = n + __popc(gm & below);
      unsigned bits = __float_as_uint(sc);
      int idx = p * (NC - 1) + (c - 1);
      if (pos < SLOTS) krow[pos] = ((ull)bits << 32) | (unsigned)(~(unsigned)idx);
      atomicAdd(&ghist[b * NBUCK + score_bucket(bits)], 1);
    }
    n += __popc(gm);
  }
  if (l16 == 0) pcount[gw] = min(n, SLOTS);
}

// Per image: inclusive suffix scan of histogram -> threshold bucket, per-bucket
// region starts (cstart, persistent) + working cursors (ccur, advanced by
// k_compact to region ends), and compact total.
__global__ __launch_bounds__(1024) void k_bound(
    const int* __restrict__ ghist, int* __restrict__ ccur, int* __restrict__ cstart,
    int* __restrict__ sboundA, int* __restrict__ ctotal) {
  __shared__ int h[NBUCK];
  __shared__ int sb;
  int b = blockIdx.x, tid = threadIdx.x;
#pragma unroll
  for (int k = 0; k < NBUCK / 1024; ++k) h[tid + k * 1024] = ghist[b * NBUCK + tid + k * 1024];
  if (tid == 0) sb = 0;
  __syncthreads();
  for (int d = 1; d < NBUCK; d <<= 1) {
    int v[NBUCK / 1024];
#pragma unroll
    for (int k = 0; k < NBUCK / 1024; ++k) {
      int i = tid + k * 1024;
      v[k] = h[i] + ((i + d < NBUCK) ? h[i + d] : 0);
    }
    __syncthreads();
#pragma unroll
    for (int k = 0; k < NBUCK / 1024; ++k) h[tid + k * 1024] = v[k];
    __syncthreads();
  }
#pragma unroll
  for (int k = 0; k < NBUCK / 1024; ++k) {
    int i = tid + k * 1024;
    if (h[i] >= KTOP && (i == NBUCK - 1 || h[i + 1] < KTOP)) sb = i;
  }
  __syncthreads();
#pragma unroll
  for (int k = 0; k < NBUCK / 1024; ++k) {
    int i = tid + k * 1024;
    int st = (i + 1 < NBUCK) ? h[i + 1] : 0;
    ccur[b * NBUCK + i] = st;
    cstart[b * NBUCK + i] = st;
  }
  if (tid == 0) {
    sboundA[b] = sb;
    ctotal[b] = h[sb];
  }
}

// Scatter passing candidates to per-bucket cursor positions (atomics spread
// over ~hundreds of bucket cursors; positions are globally unique in [0,total)
// and grouped by bucket in descending-bucket order).
__global__ __launch_bounds__(256) void k_compact(
    const ull* __restrict__ keys, const int* __restrict__ pcount,
    const int* __restrict__ sboundA, int* __restrict__ ccur,
    ull* __restrict__ ckeys) {
  int g = blockIdx.x * 256 + threadIdx.x;   // < NB*NP*SLOTS, grid exact
  int slot = g % SLOTS;
  int pp = g / SLOTS;
  int b = pp >> 13;                          // NP = 8192
  if (slot >= pcount[pp]) return;
  ull key = keys[g];
  int bk = score_bucket((unsigned)(key >> 32));
  if (bk < sboundA[b]) return;
  int pos = atomicAdd(&ccur[b * NBUCK + bk], 1);
  if (pos < SORTN) ckeys[(size_t)b * SORTN + pos] = key;
}

// Segmented rank-scatter (replaces bitonic sort): ckeys is already grouped by
// score-bucket in descending bucket order, so sorted position = region_start +
// (# region-mates with greater key). Keys unique (idx in low word) -> ranks
// are a bijection -> deterministic scatter regardless of compaction order.
__global__ __launch_bounds__(1024) void k_rank(
    const ull* __restrict__ ckeys, const int* __restrict__ ctotal,
    const int* __restrict__ cstart, const int* __restrict__ ccur,
    float* __restrict__ topk_score, int* __restrict__ topk_idx) {
  __shared__ ull sk[SORTN];
  int b = blockIdx.x, tid = threadIdx.x;
  int total = min(ctotal[b], SORTN);
  for (int i = tid; i < total; i += 1024) sk[i] = ckeys[(size_t)b * SORTN + i];
  __syncthreads();
  for (int i = tid; i < total; i += 1024) {
    ull key = sk[i];
    int bk = score_bucket((unsigned)(key >> 32));
    int s = cstart[b * NBUCK + bk];
    int e = min(ccur[b * NBUCK + bk], total);
    int r = s;
    for (int j = s; j < e; ++j) r += (sk[j] > key) ? 1 : 0;
    if (r < KTOP) {
      topk_score[b * KTOP + r] = __uint_as_float((unsigned)(key >> 32));
      topk_idx[b * KTOP + r] = (int)(~(unsigned)key);
    }
  }
  int valid_n = min(total, KTOP);
  for (int r = valid_n + tid; r < KTOP; r += 1024) {
    topk_score[b * KTOP + r] = NEGV;
    topk_idx[b * KTOP + r] = -1;
  }
}

__global__ __launch_bounds__(256) void k_decode(
    const float* __restrict__ boxreg, const float* __restrict__ props,
    const int* __restrict__ hw, const int* __restrict__ topk_idx,
    float* __restrict__ det_box, int* __restrict__ det_label,
    int* __restrict__ det_valid) {
  int g = blockIdx.x * 256 + threadIdx.x;
  if (g >= NB * KTOP) return;
  int b = g / KTOP;
  int fidx = topk_idx[g];
  if (fidx < 0) {
    det_box[(size_t)g * 4 + 0] = 0.0f;
    det_box[(size_t)g * 4 + 1] = 0.0f;
    det_box[(size_t)g * 4 + 2] = 0.0f;
    det_box[(size_t)g * 4 + 3] = 0.0f;
    det_label[g] = 0;
    det_valid[g] = 0;
    return;
  }
  int p = fidx / (NC - 1), c = fidx % (NC - 1) + 1;
  float Hf = (float)hw[0], Wf = (float)hw[1];
  float4 pr = reinterpret_cast<const float4*>(props)[b * NP + p];
  float4 rel =
      reinterpret_cast<const float4*>(boxreg + (size_t)(b * NP + p) * 4 * NC)[c];
  float x1, y1, x2, y2;
  decode_box(pr, rel, Wf, Hf, x1, y1, x2, y2);
  det_box[(size_t)g * 4 + 0] = x1;
  det_box[(size_t)g * 4 + 1] = y1;
  det_box[(size_t)g * 4 + 2] = x2;
  det_box[(size_t)g * 4 + 3] = y2;
  det_label[g] = c;
  det_valid[g] = 1;
}

// Suppression bit-matrix (labels-equal == class-offset NMS exactly, since
// offset_scale=1334 > max coord 1333 makes cross-class IoU 0).
__global__ __launch_bounds__(256) void k_mask(
    const float* __restrict__ det_box, const int* __restrict__ det_label,
    ull* __restrict__ maskmat) {
  int g = blockIdx.x * 256 + threadIdx.x;
  if (g >= NB * KTOP * 16) return;
  int w = g & 15;
  int i = (g >> 4) % KTOP;
  int b = (g >> 4) / KTOP;
  const float4* bb = reinterpret_cast<const float4*>(det_box) + (size_t)b * KTOP;
  const int* ll = det_label + b * KTOP;
  float4 bi = bb[i];
  int li = ll[i];
  float areai = (bi.z - bi.x) * (bi.w - bi.y);
  ull bits = 0;
  int j0 = w * 64;
  for (int t = 0; t < 64; ++t) {
    int j = j0 + t;
    if (j > i && j < KTOP && ll[j] == li) {
      float4 bj = bb[j];
      float areaj = (bj.z - bj.x) * (bj.w - bj.y);
      float ltx = fmaxf(bi.x, bj.x), lty = fmaxf(bi.y, bj.y);
      float rbx = fminf(bi.z, bj.z), rby = fminf(bi.w, bj.w);
      float iw = fmaxf(rbx - ltx, 0.0f), ih = fmaxf(rby - lty, 0.0f);
      float inter = iw * ih;
      float iou = inter / (areai + areaj - inter + 1e-9f);
      if (iou > NMS_T) bits |= (1ull << t);
    }
  }
  maskmat[((size_t)b * MROWS + i) * 16 + w] = bits;
}

// Windowed greedy NMS: 16 windows of 64 rows. Per window: transpose the 64x64
// intra block across lanes (6 shfl_xor stages), resolve 64 decisions with a
// register-only ballot loop, then OR kept rows' masks into 4-way-partial supp
// (all 64 lanes: group g = lane>>4 handles 16 rows, word = lane&15).
__global__ __launch_bounds__(64) void k_greedy(
    const ull* __restrict__ maskmat, const int* __restrict__ det_valid,
    int* __restrict__ keep) {
  int b = blockIdx.x;
  int lane = threadIdx.x;
  int wl = lane & 15;
  int grp = lane >> 4;
  ull validw = 0;
#pragma unroll
  for (int w = 0; w < 16; ++w) {
    int j = w * 64 + lane;
    int f = (j < KTOP) ? det_valid[b * KTOP + j] : 0;
    ull m = __ballot(f != 0);
    if (lane == w) validw = m;
  }
  ull supp = (lane < 16) ? ~validw : 0ull;  // invalid == pre-suppressed
  const ull* mrow = maskmat + (size_t)b * MROWS * 16;

  for (int w = 0; w < 16; ++w) {
    int t0 = w * 64;
    int row = t0 + lane;
    ull r = mrow[(size_t)row * 16 + w];
    if (row >= KTOP) r = 0ull;
#pragma unroll
    for (int dd = 0; dd < 6; ++dd) {
      const int d = 1 << dd;
      const ull M0 = (dd == 0) ? 0x5555555555555555ull
                   : (dd == 1) ? 0x3333333333333333ull
                   : (dd == 2) ? 0x0F0F0F0F0F0F0F0Full
                   : (dd == 3) ? 0x00FF00FF00FF00FFull
                   : (dd == 4) ? 0x0000FFFF0000FFFFull
                               : 0x00000000FFFFFFFFull;
      ull y = shfl_xor64(r, d);
      r = ((lane & d) == 0) ? ((r & M0) | ((y & M0) << d))
                            : ((r & ~M0) | ((y >> d) & M0));
    }
    ull inc = shfl64(supp, w) | shfl64(supp, w + 16) |
              shfl64(supp, w + 32) | shfl64(supp, w + 48);
    unsigned s32 = (unsigned)((inc >> lane) & 1ull);
#pragma unroll
    for (int i = 0; i < 64; ++i) {
      ull act = __ballot(s32 == 0);
      s32 |= (unsigned)(((act & r) >> i) & 1ull);
    }
    ull K = __ballot(s32 == 0);
    if (row < KTOP) keep[b * KTOP + row] = (s32 == 0) ? 1 : 0;
    ull acc = 0;
    int base_r = grp * 16;
#pragma unroll
    for (int k = 0; k < 16; ++k) {
      int i = base_r + k;
      ull v = mrow[(size_t)(t0 + i) * 16 + wl];
      if ((K >> i) & 1ull) acc |= v;
    }
    supp |= acc;
  }
}

// First 100 kept (in sorted order) -> outputs, zero-pad the rest.
__global__ __launch_bounds__(256) void k_output(
    const float* __restrict__ topk_score, const float* __restrict__ det_box,
    const int* __restrict__ det_label, const int* __restrict__ keep,
    float* __restrict__ out) {
  int b = blockIdx.x, tid = threadIdx.x;
  __shared__ int pf[1024];
  for (int i = tid; i < 1024; i += 256) pf[i] = (i < KTOP) ? keep[b * KTOP + i] : 0;
  __syncthreads();
  for (int d = 1; d < 1024; d <<= 1) {
    int v[4];
#pragma unroll
    for (int k = 0; k < 4; ++k) {
      int i = tid + k * 256;
      v[k] = pf[i] + ((i >= d) ? pf[i - d] : 0);
    }
    __syncthreads();
#pragma unroll
    for (int k = 0; k < 4; ++k) pf[tid + k * 256] = v[k];
    __syncthreads();
  }
  int total = min(pf[KTOP - 1], NDET);
  float* ob = out;
  float* os = out + (size_t)NB * NDET * 4;
  float* ol = os + (size_t)NB * NDET;
  for (int i = tid; i < KTOP; i += 256) {
    if (keep[b * KTOP + i]) {
      int r = pf[i] - 1;
      if (r < NDET) {
        ob[((size_t)b * NDET + r) * 4 + 0] = det_box[((size_t)b * KTOP + i) * 4 + 0];
        ob[((size_t)b * NDET + r) * 4 + 1] = det_box[((size_t)b * KTOP + i) * 4 + 1];
        ob[((size_t)b * NDET + r) * 4 + 2] = det_box[((size_t)b * KTOP + i) * 4 + 2];
        ob[((size_t)b * NDET + r) * 4 + 3] = det_box[((size_t)b * KTOP + i) * 4 + 3];
        os[b * NDET + r] = topk_score[b * KTOP + i];
        ol[b * NDET + r] = (float)det_label[b * KTOP + i];
      }
    }
  }
  for (int r = total + tid; r < NDET; r += 256) {
    ob[((size_t)b * NDET + r) * 4 + 0] = 0.0f;
    ob[((size_t)b * NDET + r) * 4 + 1] = 0.0f;
    ob[((size_t)b * NDET + r) * 4 + 2] = 0.0f;
    ob[((size_t)b * NDET + r) * 4 + 3] = 0.0f;
    os[b * NDET + r] = 0.0f;
    ol[b * NDET + r] = 0.0f;
  }
}

}  // namespace

extern "C" void kernel_launch(void* const* d_in, const int* in_sizes, int n_in,
                              void* d_out, int out_size, void* d_ws, size_t ws_size,
                              hipStream_t stream) {
  const float* logits = (const float*)d_in[0];
  const float* boxreg = (const float*)d_in[1];
  const float* props = (const float*)d_in[2];
  const int* hw = (const int*)d_in[3];

  char* ws = (char*)d_ws;
  size_t off = 0;
  auto alloc = [&](size_t bytes) -> void* {
    void* p = ws + off;
    off += (bytes + 255) & ~(size_t)255;
    return p;
  };
  ull* keys = (ull*)alloc((size_t)NB * NP * SLOTS * 8);
  int* pcount = (int*)alloc((size_t)NB * NP * 4);
  int* ghist = (int*)alloc((size_t)NB * NBUCK * 4);
  int* ccur = (int*)alloc((size_t)NB * NBUCK * 4);
  int* cstart = (int*)alloc((size_t)NB * NBUCK * 4);
  int* sboundA = (int*)alloc(NB * 4);
  int* ctotal = (int*)alloc(NB * 4);
  ull* ckeys = (ull*)alloc((size_t)NB * SORTN * 8);
  float* topk_score = (float*)alloc((size_t)NB * KTOP * 4);
  int* topk_idx = (int*)alloc((size_t)NB * KTOP * 4);
  float* det_box = (float*)alloc((size_t)NB * KTOP * 16);
  int* det_label = (int*)alloc((size_t)NB * KTOP * 4);
  int* det_valid = (int*)alloc((size_t)NB * KTOP * 4);
  ull* maskmat = (ull*)alloc((size_t)NB * MROWS * 16 * 8);
  int* keep = (int*)alloc((size_t)NB * KTOP * 4);

  k_zero<<<(NB * NBUCK + 255) / 256, 256, 0, stream>>>(ghist);
  k_candidates<<<(NB * NP) / 16, 256, 0, stream>>>(logits, boxreg, props, hw,
                                                   keys, pcount, ghist);
  k_bound<<<NB, 1024, 0, stream>>>(ghist, ccur, cstart, sboundA, ctotal);
  k_compact<<<(NB * NP * SLOTS) / 256, 256, 0, stream>>>(keys, pcount, sboundA, ccur, ckeys);
  k_rank<<<NB, 1024, 0, stream>>>(ckeys, ctotal, cstart, ccur, topk_score, topk_idx);
  k_decode<<<(NB * KTOP + 255) / 256, 256, 0, stream>>>(boxreg, props, hw, topk_idx,
                                                        det_box, det_label, det_valid);
  k_mask<<<(NB * KTOP * 16 + 255) / 256, 256, 0, stream>>>(det_box, det_label, maskmat);
  k_greedy<<<NB, 64, 0, stream>>>(maskmat, det_valid, keep);
  k_output<<<NB, 256, 0, stream>>>(topk_score, det_box, det_label, keep, (float*)d_out);
}

// Round 8
// 126.002 us; speedup vs baseline: 1.8013x; 1.1982x over previous
//
#include <hip/hip_runtime.h>

namespace {

constexpr int NB = 8, NP = 8192, NC = 91;
constexpr int KTOP = 1000, NDET = 100;
constexpr int MROWS = 1024;          // padded mask rows per image (16 windows of 64)
constexpr int SLOTS = 24;            // max candidates/proposal: scores sum<=1 => <=19 can be >0.05
constexpr int NBUCK = 4096, SORTN = 4096;
constexpr float SCORE_T = 0.05f;
constexpr float MIN_SZ = 0.01f;
constexpr float NMS_T = 0.5f;
constexpr float CLIPV = 4.135166556742356f;  // log(1000/16)
constexpr float NEGV = -1e9f;

typedef unsigned long long ull;

__device__ __forceinline__ void decode_box(const float4& pr, const float4& rel,
                                           float Wf, float Hf,
                                           float& x1, float& y1, float& x2, float& y2) {
  float w = pr.z - pr.x, h = pr.w - pr.y;
  float cx = pr.x + 0.5f * w, cy = pr.y + 0.5f * h;
  float dx = rel.x / 10.0f, dy = rel.y / 10.0f;
  float dw = fminf(rel.z / 5.0f, CLIPV), dh = fminf(rel.w / 5.0f, CLIPV);
  float pcx = dx * w + cx, pcy = dy * h + cy;
  float pw = expf(dw) * w, ph = expf(dh) * h;
  x1 = fminf(fmaxf(pcx - 0.5f * pw, 0.0f), Wf);
  y1 = fminf(fmaxf(pcy - 0.5f * ph, 0.0f), Hf);
  x2 = fminf(fmaxf(pcx + 0.5f * pw, 0.0f), Wf);
  y2 = fminf(fmaxf(pcy + 0.5f * ph, 0.0f), Hf);
}

__device__ __forceinline__ int score_bucket(unsigned bits) {
  return min((int)((bits - 0x3D000000u) >> 14), NBUCK - 1);
}

__device__ __forceinline__ ull shfl64(ull v, int src) {
  int lo = __shfl((int)(unsigned)(v & 0xffffffffull), src, 64);
  int hi = __shfl((int)(unsigned)(v >> 32), src, 64);
  return ((ull)(unsigned)hi << 32) | (unsigned)lo;
}

__device__ __forceinline__ ull shfl_xor64(ull v, int d) {
  int lo = __shfl_xor((int)(unsigned)(v & 0xffffffffull), d, 64);
  int hi = __shfl_xor((int)(unsigned)(v >> 32), d, 64);
  return ((ull)(unsigned)hi << 32) | (unsigned)lo;
}

__global__ __launch_bounds__(256) void k_zero(int* ghist) {
  int g = blockIdx.x * 256 + threadIdx.x;
  if (g < NB * NBUCK) ghist[g] = 0;
}

// 16-lane group per proposal (4 proposals/wave, no LDS): 6 coalesced strip
// loads keep the row in registers (zreg[6]); 4-stage group shfl reductions for
// max and sum; candidate pass reuses zreg with logit-domain prefilter (strict
// superset, -1e-3 margin) before the exact score test. Deterministic 24-slot
// output region per proposal: no contended atomics.
__global__ __launch_bounds__(256) void k_candidates(
    const float* __restrict__ logits, const float* __restrict__ boxreg,
    const float* __restrict__ props, const int* __restrict__ hw,
    ull* __restrict__ keys, int* __restrict__ pcount, int* __restrict__ ghist) {
  int tid = threadIdx.x;
  int lane = tid & 63;
  int l16 = lane & 15;
  int grp = lane >> 4;
  int wv = tid >> 6;
  int gw = blockIdx.x * 16 + wv * 4 + grp;   // proposal; grid exact, image-uniform per block
  int b = gw >> 13;                           // NP = 8192
  int p = gw & (NP - 1);
  float Hf = (float)hw[0], Wf = (float)hw[1];
  const float* lrow = logits + (size_t)gw * NC;

  float zreg[6];
  float m = -3.0e38f;
#pragma unroll
  for (int k = 0; k < 6; ++k) {
    int c = k * 16 + l16;
    float z = (c < NC) ? lrow[c] : -3.0e38f;
    zreg[k] = z;
    m = fmaxf(m, z);
  }
#pragma unroll
  for (int d = 1; d < 16; d <<= 1) m = fmaxf(m, __shfl_xor(m, d, 64));
  float S = 0.0f;
#pragma unroll
  for (int k = 0; k < 6; ++k) {
    int c = k * 16 + l16;
    S += (c < NC) ? expf(zreg[k] - m) : 0.0f;
  }
#pragma unroll
  for (int d = 1; d < 16; d <<= 1) S += __shfl_xor(S, d, 64);

  float invS = 1.0f / S;
  float thr = m + logf(SCORE_T * S) - 1e-3f;   // superset prefilter

  float4 pr = reinterpret_cast<const float4*>(props)[gw];
  const float4* relrow = reinterpret_cast<const float4*>(boxreg + (size_t)gw * 4 * NC);
  ull* krow = keys + (size_t)gw * SLOTS;
  unsigned below = (1u << l16) - 1u;
  int n = 0;
#pragma unroll
  for (int k = 0; k < 6; ++k) {
    int c = k * 16 + l16;
    bool ok = (c >= 1) && (c < NC) && (zreg[k] > thr);
    float sc = 0.0f;
    if (ok) {
      sc = expf(zreg[k] - m) * invS;
      ok = sc > SCORE_T;
      if (ok) {
        float4 rel = relrow[c];
        float x1, y1, x2, y2;
        decode_box(pr, rel, Wf, Hf, x1, y1, x2, y2);
        ok = ((x2 - x1) >= MIN_SZ) && ((y2 - y1) >= MIN_SZ);
      }
    }
    ull bal = __ballot(ok);
    unsigned gm = (unsigned)((bal >> (grp * 16)) & 0xFFFFull);
    if (ok) {
      int pos = n + __popc(gm & below);
      unsigned bits = __float_as_uint(sc);
      int idx = p * (NC - 1) + (c - 1);
      if (pos < SLOTS) krow[pos] = ((ull)bits << 32) | (unsigned)(~(unsigned)idx);
      atomicAdd(&ghist[b * NBUCK + score_bucket(bits)], 1);
    }
    n += __popc(gm);
  }
  if (l16 == 0) pcount[gw] = min(n, SLOTS);
}

// Per image: inclusive suffix scan of histogram -> threshold bucket, per-bucket
// region starts (cstart, persistent) + working cursors (ccur, advanced by
// k_compact to region ends), and compact total.
__global__ __launch_bounds__(1024) void k_bound(
    const int* __restrict__ ghist, int* __restrict__ ccur, int* __restrict__ cstart,
    int* __restrict__ sboundA, int* __restrict__ ctotal) {
  __shared__ int h[NBUCK];
  __shared__ int sb;
  int b = blockIdx.x, tid = threadIdx.x;
#pragma unroll
  for (int k = 0; k < NBUCK / 1024; ++k) h[tid + k * 1024] = ghist[b * NBUCK + tid + k * 1024];
  if (tid == 0) sb = 0;
  __syncthreads();
  for (int d = 1; d < NBUCK; d <<= 1) {
    int v[NBUCK / 1024];
#pragma unroll
    for (int k = 0; k < NBUCK / 1024; ++k) {
      int i = tid + k * 1024;
      v[k] = h[i] + ((i + d < NBUCK) ? h[i + d] : 0);
    }
    __syncthreads();
#pragma unroll
    for (int k = 0; k < NBUCK / 1024; ++k) h[tid + k * 1024] = v[k];
    __syncthreads();
  }
#pragma unroll
  for (int k = 0; k < NBUCK / 1024; ++k) {
    int i = tid + k * 1024;
    if (h[i] >= KTOP && (i == NBUCK - 1 || h[i + 1] < KTOP)) sb = i;
  }
  __syncthreads();
#pragma unroll
  for (int k = 0; k < NBUCK / 1024; ++k) {
    int i = tid + k * 1024;
    int st = (i + 1 < NBUCK) ? h[i + 1] : 0;
    ccur[b * NBUCK + i] = st;
    cstart[b * NBUCK + i] = st;
  }
  if (tid == 0) {
    sboundA[b] = sb;
    ctotal[b] = h[sb];
  }
}

// Scatter passing candidates to per-bucket cursor positions (atomics spread
// over ~hundreds of bucket cursors; positions are globally unique in [0,total)
// and grouped by bucket in descending-bucket order).
__global__ __launch_bounds__(256) void k_compact(
    const ull* __restrict__ keys, const int* __restrict__ pcount,
    const int* __restrict__ sboundA, int* __restrict__ ccur,
    ull* __restrict__ ckeys) {
  int g = blockIdx.x * 256 + threadIdx.x;   // < NB*NP*SLOTS, grid exact
  int slot = g % SLOTS;
  int pp = g / SLOTS;
  int b = pp >> 13;                          // NP = 8192
  if (slot >= pcount[pp]) return;
  ull key = keys[g];
  int bk = score_bucket((unsigned)(key >> 32));
  if (bk < sboundA[b]) return;
  int pos = atomicAdd(&ccur[b * NBUCK + bk], 1);
  if (pos < SORTN) ckeys[(size_t)b * SORTN + pos] = key;
}

// Segmented rank-scatter (replaces bitonic sort): ckeys is already grouped by
// score-bucket in descending bucket order, so sorted position = region_start +
// (# region-mates with greater key). Keys unique (idx in low word) -> ranks
// are a bijection -> deterministic scatter regardless of compaction order.
__global__ __launch_bounds__(1024) void k_rank(
    const ull* __restrict__ ckeys, const int* __restrict__ ctotal,
    const int* __restrict__ cstart, const int* __restrict__ ccur,
    float* __restrict__ topk_score, int* __restrict__ topk_idx) {
  __shared__ ull sk[SORTN];
  int b = blockIdx.x, tid = threadIdx.x;
  int total = min(ctotal[b], SORTN);
  for (int i = tid; i < total; i += 1024) sk[i] = ckeys[(size_t)b * SORTN + i];
  __syncthreads();
  for (int i = tid; i < total; i += 1024) {
    ull key = sk[i];
    int bk = score_bucket((unsigned)(key >> 32));
    int s = cstart[b * NBUCK + bk];
    int e = min(ccur[b * NBUCK + bk], total);
    int r = s;
    for (int j = s; j < e; ++j) r += (sk[j] > key) ? 1 : 0;
    if (r < KTOP) {
      topk_score[b * KTOP + r] = __uint_as_float((unsigned)(key >> 32));
      topk_idx[b * KTOP + r] = (int)(~(unsigned)key);
    }
  }
  int valid_n = min(total, KTOP);
  for (int r = valid_n + tid; r < KTOP; r += 1024) {
    topk_score[b * KTOP + r] = NEGV;
    topk_idx[b * KTOP + r] = -1;
  }
}

__global__ __launch_bounds__(256) void k_decode(
    const float* __restrict__ boxreg, const float* __restrict__ props,
    const int* __restrict__ hw, const int* __restrict__ topk_idx,
    float* __restrict__ det_box, int* __restrict__ det_label,
    int* __restrict__ det_valid) {
  int g = blockIdx.x * 256 + threadIdx.x;
  if (g >= NB * KTOP) return;
  int b = g / KTOP;
  int fidx = topk_idx[g];
  if (fidx < 0) {
    det_box[(size_t)g * 4 + 0] = 0.0f;
    det_box[(size_t)g * 4 + 1] = 0.0f;
    det_box[(size_t)g * 4 + 2] = 0.0f;
    det_box[(size_t)g * 4 + 3] = 0.0f;
    det_label[g] = 0;
    det_valid[g] = 0;
    return;
  }
  int p = fidx / (NC - 1), c = fidx % (NC - 1) + 1;
  float Hf = (float)hw[0], Wf = (float)hw[1];
  float4 pr = reinterpret_cast<const float4*>(props)[b * NP + p];
  float4 rel =
      reinterpret_cast<const float4*>(boxreg + (size_t)(b * NP + p) * 4 * NC)[c];
  float x1, y1, x2, y2;
  decode_box(pr, rel, Wf, Hf, x1, y1, x2, y2);
  det_box[(size_t)g * 4 + 0] = x1;
  det_box[(size_t)g * 4 + 1] = y1;
  det_box[(size_t)g * 4 + 2] = x2;
  det_box[(size_t)g * 4 + 3] = y2;
  det_label[g] = c;
  det_valid[g] = 1;
}

// Suppression bit-matrix (labels-equal == class-offset NMS exactly, since
// offset_scale=1334 > max coord 1333 makes cross-class IoU 0) + per-row 16-bit
// nonzero-word bitmap (nzmap) via 16-lane ballot.
__global__ __launch_bounds__(256) void k_mask(
    const float* __restrict__ det_box, const int* __restrict__ det_label,
    ull* __restrict__ maskmat, unsigned short* __restrict__ nzmap) {
  int g = blockIdx.x * 256 + threadIdx.x;   // grid exact: NB*KTOP*16 = 128000
  int w = g & 15;
  int i = (g >> 4) % KTOP;
  int b = (g >> 4) / KTOP;
  const float4* bb = reinterpret_cast<const float4*>(det_box) + (size_t)b * KTOP;
  const int* ll = det_label + b * KTOP;
  float4 bi = bb[i];
  int li = ll[i];
  float areai = (bi.z - bi.x) * (bi.w - bi.y);
  ull bits = 0;
  int j0 = w * 64;
  for (int t = 0; t < 64; ++t) {
    int j = j0 + t;
    if (j > i && j < KTOP && ll[j] == li) {
      float4 bj = bb[j];
      float areaj = (bj.z - bj.x) * (bj.w - bj.y);
      float ltx = fmaxf(bi.x, bj.x), lty = fmaxf(bi.y, bj.y);
      float rbx = fminf(bi.z, bj.z), rby = fminf(bi.w, bj.w);
      float iw = fmaxf(rbx - ltx, 0.0f), ih = fmaxf(rby - lty, 0.0f);
      float inter = iw * ih;
      float iou = inter / (areai + areaj - inter + 1e-9f);
      if (iou > NMS_T) bits |= (1ull << t);
    }
  }
  maskmat[((size_t)b * MROWS + i) * 16 + w] = bits;
  ull bal = __ballot(bits != 0ull);
  if (w == 0)
    nzmap[b * MROWS + i] = (unsigned short)((bal >> (threadIdx.x & 48)) & 0xFFFFull);
}

// Windowed greedy NMS with sparsity fast paths (exact short-circuits):
//  - all intra/nz words preloaded to registers (off the serial chain)
//  - supp fully replicated per lane (word lane&15) -> inc is ONE shfl64
//  - skip transpose+64-iter loop when the window has no intra edges
//  - skip the 16 acc loads when no kept row has a nonzero mask word
__global__ __launch_bounds__(64) void k_greedy(
    const ull* __restrict__ maskmat, const unsigned short* __restrict__ nzmap,
    const int* __restrict__ det_valid, int* __restrict__ keep) {
  int b = blockIdx.x;
  int lane = threadIdx.x;
  int wl = lane & 15;
  int grp = lane >> 4;
  const ull* mrow = maskmat + (size_t)b * MROWS * 16;

  // preload: rr[k] = intra word of row k*64+lane; nzr[k] = its nonzero map
  ull rr[16];
  unsigned nzr[16];
#pragma unroll
  for (int k = 0; k < 16; ++k) {
    int row = k * 64 + lane;
    rr[k] = mrow[(size_t)row * 16 + k];
    unsigned nz = nzmap[b * MROWS + row];
    if (row >= KTOP) { rr[k] = 0ull; nz = 0u; }
    nzr[k] = nz & ~(1u << k);        // ignore intra word (handled by rr)
  }

  // valid words: lane w<16 collects word w, then replicate to all lanes by wl
  ull validw = 0;
#pragma unroll
  for (int w = 0; w < 16; ++w) {
    int j = w * 64 + lane;
    int f = (j < KTOP) ? det_valid[b * KTOP + j] : 0;
    ull m = __ballot(f != 0);
    if (lane == w) validw = m;
  }
  ull supp = ~shfl64(validw, wl);    // invalid == pre-suppressed; full word per lane

  for (int w = 0; w < 16; ++w) {
    int t0 = w * 64;
    int row = t0 + lane;
    ull inc = shfl64(supp, w);
    unsigned s32 = (unsigned)((inc >> lane) & 1ull);
    ull r = rr[w];
    if (__ballot(r != 0ull)) {       // rare: intra-window edges exist
      // transpose 64x64 bit block: after, bit i of lane l = M[t0+i][t0+l]
#pragma unroll
      for (int dd = 0; dd < 6; ++dd) {
        const int d = 1 << dd;
        const ull M0 = (dd == 0) ? 0x5555555555555555ull
                     : (dd == 1) ? 0x3333333333333333ull
                     : (dd == 2) ? 0x0F0F0F0F0F0F0F0Full
                     : (dd == 3) ? 0x00FF00FF00FF00FFull
                     : (dd == 4) ? 0x0000FFFF0000FFFFull
                                 : 0x00000000FFFFFFFFull;
        ull y = shfl_xor64(r, d);
        r = ((lane & d) == 0) ? ((r & M0) | ((y & M0) << d))
                              : ((r & ~M0) | ((y >> d) & M0));
      }
#pragma unroll
      for (int i = 0; i < 64; ++i) {
        ull act = __ballot(s32 == 0);
        s32 |= (unsigned)(((act & r) >> i) & 1ull);
      }
    }
    ull K = __ballot(s32 == 0);
    if (row < KTOP) keep[b * KTOP + row] = (s32 == 0) ? 1 : 0;
    if (__ballot((((K >> lane) & 1ull) != 0ull) && (nzr[w] != 0u))) {  // rare
      ull acc = 0;
      int base_r = grp * 16;
#pragma unroll
      for (int k = 0; k < 16; ++k) {
        int i = base_r + k;
        ull v = mrow[(size_t)(t0 + i) * 16 + wl];
        if ((K >> i) & 1ull) acc |= v;
      }
      acc |= shfl_xor64(acc, 16);
      acc |= shfl_xor64(acc, 32);
      supp |= acc;
    }
  }
}

// First 100 kept (in sorted order) -> outputs, zero-pad the rest.
__global__ __launch_bounds__(256) void k_output(
    const float* __restrict__ topk_score, const float* __restrict__ det_box,
    const int* __restrict__ det_label, const int* __restrict__ keep,
    float* __restrict__ out) {
  int b = blockIdx.x, tid = threadIdx.x;
  __shared__ int pf[1024];
  for (int i = tid; i < 1024; i += 256) pf[i] = (i < KTOP) ? keep[b * KTOP + i] : 0;
  __syncthreads();
  for (int d = 1; d < 1024; d <<= 1) {
    int v[4];
#pragma unroll
    for (int k = 0; k < 4; ++k) {
      int i = tid + k * 256;
      v[k] = pf[i] + ((i >= d) ? pf[i - d] : 0);
    }
    __syncthreads();
#pragma unroll
    for (int k = 0; k < 4; ++k) pf[tid + k * 256] = v[k];
    __syncthreads();
  }
  int total = min(pf[KTOP - 1], NDET);
  float* ob = out;
  float* os = out + (size_t)NB * NDET * 4;
  float* ol = os + (size_t)NB * NDET;
  for (int i = tid; i < KTOP; i += 256) {
    if (keep[b * KTOP + i]) {
      int r = pf[i] - 1;
      if (r < NDET) {
        ob[((size_t)b * NDET + r) * 4 + 0] = det_box[((size_t)b * KTOP + i) * 4 + 0];
        ob[((size_t)b * NDET + r) * 4 + 1] = det_box[((size_t)b * KTOP + i) * 4 + 1];
        ob[((size_t)b * NDET + r) * 4 + 2] = det_box[((size_t)b * KTOP + i) * 4 + 2];
        ob[((size_t)b * NDET + r) * 4 + 3] = det_box[((size_t)b * KTOP + i) * 4 + 3];
        os[b * NDET + r] = topk_score[b * KTOP + i];
        ol[b * NDET + r] = (float)det_label[b * KTOP + i];
      }
    }
  }
  for (int r = total + tid; r < NDET; r += 256) {
    ob[((size_t)b * NDET + r) * 4 + 0] = 0.0f;
    ob[((size_t)b * NDET + r) * 4 + 1] = 0.0f;
    ob[((size_t)b * NDET + r) * 4 + 2] = 0.0f;
    ob[((size_t)b * NDET + r) * 4 + 3] = 0.0f;
    os[b * NDET + r] = 0.0f;
    ol[b * NDET + r] = 0.0f;
  }
}

}  // namespace

extern "C" void kernel_launch(void* const* d_in, const int* in_sizes, int n_in,
                              void* d_out, int out_size, void* d_ws, size_t ws_size,
                              hipStream_t stream) {
  const float* logits = (const float*)d_in[0];
  const float* boxreg = (const float*)d_in[1];
  const float* props = (const float*)d_in[2];
  const int* hw = (const int*)d_in[3];

  char* ws = (char*)d_ws;
  size_t off = 0;
  auto alloc = [&](size_t bytes) -> void* {
    void* p = ws + off;
    off += (bytes + 255) & ~(size_t)255;
    return p;
  };
  ull* keys = (ull*)alloc((size_t)NB * NP * SLOTS * 8);
  int* pcount = (int*)alloc((size_t)NB * NP * 4);
  int* ghist = (int*)alloc((size_t)NB * NBUCK * 4);
  int* ccur = (int*)alloc((size_t)NB * NBUCK * 4);
  int* cstart = (int*)alloc((size_t)NB * NBUCK * 4);
  int* sboundA = (int*)alloc(NB * 4);
  int* ctotal = (int*)alloc(NB * 4);
  ull* ckeys = (ull*)alloc((size_t)NB * SORTN * 8);
  float* topk_score = (float*)alloc((size_t)NB * KTOP * 4);
  int* topk_idx = (int*)alloc((size_t)NB * KTOP * 4);
  float* det_box = (float*)alloc((size_t)NB * KTOP * 16);
  int* det_label = (int*)alloc((size_t)NB * KTOP * 4);
  int* det_valid = (int*)alloc((size_t)NB * KTOP * 4);
  ull* maskmat = (ull*)alloc((size_t)NB * MROWS * 16 * 8);
  unsigned short* nzmap = (unsigned short*)alloc((size_t)NB * MROWS * 2);
  int* keep = (int*)alloc((size_t)NB * KTOP * 4);

  k_zero<<<(NB * NBUCK + 255) / 256, 256, 0, stream>>>(ghist);
  k_candidates<<<(NB * NP) / 16, 256, 0, stream>>>(logits, boxreg, props, hw,
                                                   keys, pcount, ghist);
  k_bound<<<NB, 1024, 0, stream>>>(ghist, ccur, cstart, sboundA, ctotal);
  k_compact<<<(NB * NP * SLOTS) / 256, 256, 0, stream>>>(keys, pcount, sboundA, ccur, ckeys);
  k_rank<<<NB, 1024, 0, stream>>>(ckeys, ctotal, cstart, ccur, topk_score, topk_idx);
  k_decode<<<(NB * KTOP + 255) / 256, 256, 0, stream>>>(boxreg, props, hw, topk_idx,
                                                        det_box, det_label, det_valid);
  k_mask<<<(NB * KTOP * 16 + 255) / 256, 256, 0, stream>>>(det_box, det_label, maskmat, nzmap);
  k_greedy<<<NB, 64, 0, stream>>>(maskmat, nzmap, det_valid, keep);
  k_output<<<NB, 256, 0, stream>>>(topk_score, det_box, det_label, keep, (float*)d_out);
}

// Round 9
// 119.131 us; speedup vs baseline: 1.9052x; 1.0577x over previous
//
#include <hip/hip_runtime.h>

namespace {

constexpr int NB = 8, NP = 8192, NC = 91;
constexpr int KTOP = 1000, NDET = 100;
constexpr int MROWS = 1024;          // padded mask rows per image (16 windows of 64)
constexpr int SLOTS = 24;            // max candidates/proposal: scores sum<=1 => <=19 can be >0.05
constexpr int NBUCK = 4096, SORTN = 4096;
constexpr float SCORE_T = 0.05f;
constexpr float MIN_SZ = 0.01f;
constexpr float NMS_T = 0.5f;
constexpr float CLIPV = 4.135166556742356f;  // log(1000/16)
constexpr float NEGV = -1e9f;

typedef unsigned long long ull;

__device__ __forceinline__ void decode_box(const float4& pr, const float4& rel,
                                           float Wf, float Hf,
                                           float& x1, float& y1, float& x2, float& y2) {
  float w = pr.z - pr.x, h = pr.w - pr.y;
  float cx = pr.x + 0.5f * w, cy = pr.y + 0.5f * h;
  float dx = rel.x / 10.0f, dy = rel.y / 10.0f;
  float dw = fminf(rel.z / 5.0f, CLIPV), dh = fminf(rel.w / 5.0f, CLIPV);
  float pcx = dx * w + cx, pcy = dy * h + cy;
  float pw = expf(dw) * w, ph = expf(dh) * h;
  x1 = fminf(fmaxf(pcx - 0.5f * pw, 0.0f), Wf);
  y1 = fminf(fmaxf(pcy - 0.5f * ph, 0.0f), Hf);
  x2 = fminf(fmaxf(pcx + 0.5f * pw, 0.0f), Wf);
  y2 = fminf(fmaxf(pcy + 0.5f * ph, 0.0f), Hf);
}

__device__ __forceinline__ int score_bucket(unsigned bits) {
  return min((int)((bits - 0x3D000000u) >> 14), NBUCK - 1);
}

__device__ __forceinline__ ull shfl64(ull v, int src) {
  int lo = __shfl((int)(unsigned)(v & 0xffffffffull), src, 64);
  int hi = __shfl((int)(unsigned)(v >> 32), src, 64);
  return ((ull)(unsigned)hi << 32) | (unsigned)lo;
}

__device__ __forceinline__ ull shfl_xor64(ull v, int d) {
  int lo = __shfl_xor((int)(unsigned)(v & 0xffffffffull), d, 64);
  int hi = __shfl_xor((int)(unsigned)(v >> 32), d, 64);
  return ((ull)(unsigned)hi << 32) | (unsigned)lo;
}

__global__ __launch_bounds__(256) void k_zero(int* ghist) {
  int g = blockIdx.x * 256 + threadIdx.x;
  if (g < NB * NBUCK) ghist[g] = 0;
}

// 16-lane group per proposal; 16 proposals per 256-thread block staged through
// 5.8KB LDS (float4-coalesced: block base = 16*91*4 = 5824B, 16B-aligned).
// Occupancy-safe (R5's 46.6KB/block cliff avoided). Same reduction math as the
// passing register version; logit-domain prefilter (strict superset, -1e-3
// margin) gates the exact score test. Deterministic 24-slot region/proposal.
__global__ __launch_bounds__(256) void k_candidates(
    const float* __restrict__ logits, const float* __restrict__ boxreg,
    const float* __restrict__ props, const int* __restrict__ hw,
    ull* __restrict__ keys, int* __restrict__ pcount, int* __restrict__ ghist) {
  __shared__ float sh[16 * NC];              // 1456 floats
  int tid = threadIdx.x;
  int base = blockIdx.x * 16;
  const float4* src4 = reinterpret_cast<const float4*>(logits + (size_t)base * NC);
  float4* sh4 = reinterpret_cast<float4*>(sh);
  for (int i = tid; i < (16 * NC) / 4; i += 256) sh4[i] = src4[i];
  __syncthreads();

  int lane = tid & 63;
  int l16 = lane & 15;
  int grp = lane >> 4;
  int wv = tid >> 6;
  int lp = wv * 4 + grp;                     // local proposal 0..15
  int gw = base + lp;
  int b = gw >> 13;                          // NP = 8192
  int p = gw & (NP - 1);
  float Hf = (float)hw[0], Wf = (float)hw[1];
  const float* row = sh + lp * NC;

  float zreg[6];
  float m = -3.0e38f;
#pragma unroll
  for (int k = 0; k < 6; ++k) {
    int c = k * 16 + l16;
    float z = (c < NC) ? row[c] : -3.0e38f;
    zreg[k] = z;
    m = fmaxf(m, z);
  }
#pragma unroll
  for (int d = 1; d < 16; d <<= 1) m = fmaxf(m, __shfl_xor(m, d, 64));
  float S = 0.0f;
#pragma unroll
  for (int k = 0; k < 6; ++k) {
    int c = k * 16 + l16;
    S += (c < NC) ? expf(zreg[k] - m) : 0.0f;
  }
#pragma unroll
  for (int d = 1; d < 16; d <<= 1) S += __shfl_xor(S, d, 64);

  float invS = 1.0f / S;
  float thr = m + logf(SCORE_T * S) - 1e-3f;   // superset prefilter

  float4 pr = reinterpret_cast<const float4*>(props)[gw];
  const float4* relrow = reinterpret_cast<const float4*>(boxreg + (size_t)gw * 4 * NC);
  ull* krow = keys + (size_t)gw * SLOTS;
  unsigned below = (1u << l16) - 1u;
  int n = 0;
#pragma unroll
  for (int k = 0; k < 6; ++k) {
    int c = k * 16 + l16;
    bool ok = (c >= 1) && (c < NC) && (zreg[k] > thr);
    float sc = 0.0f;
    if (ok) {
      sc = expf(zreg[k] - m) * invS;
      ok = sc > SCORE_T;
      if (ok) {
        float4 rel = relrow[c];
        float x1, y1, x2, y2;
        decode_box(pr, rel, Wf, Hf, x1, y1, x2, y2);
        ok = ((x2 - x1) >= MIN_SZ) && ((y2 - y1) >= MIN_SZ);
      }
    }
    ull bal = __ballot(ok);
    unsigned gm = (unsigned)((bal >> (grp * 16)) & 0xFFFFull);
    if (ok) {
      int pos = n + __popc(gm & below);
      unsigned bits = __float_as_uint(sc);
      int idx = p * (NC - 1) + (c - 1);
      if (pos < SLOTS) krow[pos] = ((ull)bits << 32) | (unsigned)(~(unsigned)idx);
      atomicAdd(&ghist[b * NBUCK + score_bucket(bits)], 1);
    }
    n += __popc(gm);
  }
  if (l16 == 0) pcount[gw] = min(n, SLOTS);
}

// Per image: inclusive suffix scan of histogram -> threshold bucket, per-bucket
// region starts (cstart, persistent) + working cursors (ccur, advanced by
// k_compact to region ends), and compact total.
__global__ __launch_bounds__(1024) void k_bound(
    const int* __restrict__ ghist, int* __restrict__ ccur, int* __restrict__ cstart,
    int* __restrict__ sboundA, int* __restrict__ ctotal) {
  __shared__ int h[NBUCK];
  __shared__ int sb;
  int b = blockIdx.x, tid = threadIdx.x;
#pragma unroll
  for (int k = 0; k < NBUCK / 1024; ++k) h[tid + k * 1024] = ghist[b * NBUCK + tid + k * 1024];
  if (tid == 0) sb = 0;
  __syncthreads();
  for (int d = 1; d < NBUCK; d <<= 1) {
    int v[NBUCK / 1024];
#pragma unroll
    for (int k = 0; k < NBUCK / 1024; ++k) {
      int i = tid + k * 1024;
      v[k] = h[i] + ((i + d < NBUCK) ? h[i + d] : 0);
    }
    __syncthreads();
#pragma unroll
    for (int k = 0; k < NBUCK / 1024; ++k) h[tid + k * 1024] = v[k];
    __syncthreads();
  }
#pragma unroll
  for (int k = 0; k < NBUCK / 1024; ++k) {
    int i = tid + k * 1024;
    if (h[i] >= KTOP && (i == NBUCK - 1 || h[i + 1] < KTOP)) sb = i;
  }
  __syncthreads();
#pragma unroll
  for (int k = 0; k < NBUCK / 1024; ++k) {
    int i = tid + k * 1024;
    int st = (i + 1 < NBUCK) ? h[i + 1] : 0;
    ccur[b * NBUCK + i] = st;
    cstart[b * NBUCK + i] = st;
  }
  if (tid == 0) {
    sboundA[b] = sb;
    ctotal[b] = h[sb];
  }
}

// Thread-per-proposal compaction (one pcount read, loop over <=SLOTS slots).
// Atomics spread over ~hundreds of bucket cursors; positions globally unique
// in [0,total), grouped by bucket in descending-bucket order.
__global__ __launch_bounds__(256) void k_compact(
    const ull* __restrict__ keys, const int* __restrict__ pcount,
    const int* __restrict__ sboundA, int* __restrict__ ccur,
    ull* __restrict__ ckeys) {
  int pp = blockIdx.x * 256 + threadIdx.x;   // < NB*NP, grid exact
  int b = pp >> 13;                          // NP = 8192
  int n = pcount[pp];
  int sb = sboundA[b];
  const ull* krow = keys + (size_t)pp * SLOTS;
  for (int s = 0; s < n; ++s) {
    ull key = krow[s];
    int bk = score_bucket((unsigned)(key >> 32));
    if (bk < sb) continue;
    int pos = atomicAdd(&ccur[b * NBUCK + bk], 1);
    if (pos < SORTN) ckeys[(size_t)b * SORTN + pos] = key;
  }
}

// Fused segmented rank-scatter + decode: ckeys is grouped by score-bucket in
// descending bucket order, so sorted position = region_start + (# region-mates
// with greater key). Keys unique -> bijective ranks -> the thread that ranks a
// key also decodes its box straight into det_* at position r. Pad the tail.
__global__ __launch_bounds__(1024) void k_rankdec(
    const ull* __restrict__ ckeys, const int* __restrict__ ctotal,
    const int* __restrict__ cstart, const int* __restrict__ ccur,
    const float* __restrict__ boxreg, const float* __restrict__ props,
    const int* __restrict__ hw,
    float* __restrict__ topk_score, float* __restrict__ det_box,
    int* __restrict__ det_label, int* __restrict__ det_valid) {
  __shared__ ull sk[SORTN];
  int b = blockIdx.x, tid = threadIdx.x;
  int total = min(ctotal[b], SORTN);
  float Hf = (float)hw[0], Wf = (float)hw[1];
  for (int i = tid; i < total; i += 1024) sk[i] = ckeys[(size_t)b * SORTN + i];
  __syncthreads();
  for (int i = tid; i < total; i += 1024) {
    ull key = sk[i];
    int bk = score_bucket((unsigned)(key >> 32));
    int s = cstart[b * NBUCK + bk];
    int e = min(ccur[b * NBUCK + bk], total);
    int r = s;
    for (int j = s; j < e; ++j) r += (sk[j] > key) ? 1 : 0;
    if (r < KTOP) {
      int g = b * KTOP + r;
      topk_score[g] = __uint_as_float((unsigned)(key >> 32));
      int fidx = (int)(~(unsigned)key);
      int p = fidx / (NC - 1), c = fidx % (NC - 1) + 1;
      float4 pr = reinterpret_cast<const float4*>(props)[b * NP + p];
      float4 rel =
          reinterpret_cast<const float4*>(boxreg + (size_t)(b * NP + p) * 4 * NC)[c];
      float x1, y1, x2, y2;
      decode_box(pr, rel, Wf, Hf, x1, y1, x2, y2);
      det_box[(size_t)g * 4 + 0] = x1;
      det_box[(size_t)g * 4 + 1] = y1;
      det_box[(size_t)g * 4 + 2] = x2;
      det_box[(size_t)g * 4 + 3] = y2;
      det_label[g] = c;
      det_valid[g] = 1;
    }
  }
  int valid_n = min(total, KTOP);
  for (int r = valid_n + tid; r < KTOP; r += 1024) {
    int g = b * KTOP + r;
    topk_score[g] = NEGV;
    det_box[(size_t)g * 4 + 0] = 0.0f;
    det_box[(size_t)g * 4 + 1] = 0.0f;
    det_box[(size_t)g * 4 + 2] = 0.0f;
    det_box[(size_t)g * 4 + 3] = 0.0f;
    det_label[g] = 0;
    det_valid[g] = 0;
  }
}

// Suppression bit-matrix (labels-equal == class-offset NMS exactly, since
// offset_scale=1334 > max coord 1333 makes cross-class IoU 0) + per-row 16-bit
// nonzero-word bitmap (nzmap) via 16-lane ballot.
__global__ __launch_bounds__(256) void k_mask(
    const float* __restrict__ det_box, const int* __restrict__ det_label,
    ull* __restrict__ maskmat, unsigned short* __restrict__ nzmap) {
  int g = blockIdx.x * 256 + threadIdx.x;   // grid exact: NB*KTOP*16 = 128000
  int w = g & 15;
  int i = (g >> 4) % KTOP;
  int b = (g >> 4) / KTOP;
  const float4* bb = reinterpret_cast<const float4*>(det_box) + (size_t)b * KTOP;
  const int* ll = det_label + b * KTOP;
  float4 bi = bb[i];
  int li = ll[i];
  float areai = (bi.z - bi.x) * (bi.w - bi.y);
  ull bits = 0;
  int j0 = w * 64;
  for (int t = 0; t < 64; ++t) {
    int j = j0 + t;
    if (j > i && j < KTOP && ll[j] == li) {
      float4 bj = bb[j];
      float areaj = (bj.z - bj.x) * (bj.w - bj.y);
      float ltx = fmaxf(bi.x, bj.x), lty = fmaxf(bi.y, bj.y);
      float rbx = fminf(bi.z, bj.z), rby = fminf(bi.w, bj.w);
      float iw = fmaxf(rbx - ltx, 0.0f), ih = fmaxf(rby - lty, 0.0f);
      float inter = iw * ih;
      float iou = inter / (areai + areaj - inter + 1e-9f);
      if (iou > NMS_T) bits |= (1ull << t);
    }
  }
  maskmat[((size_t)b * MROWS + i) * 16 + w] = bits;
  ull bal = __ballot(bits != 0ull);
  if (w == 0)
    nzmap[b * MROWS + i] = (unsigned short)((bal >> (threadIdx.x & 48)) & 0xFFFFull);
}

// Fused windowed greedy NMS (wave 0) + output emit (all 256 threads).
// Greedy keeps R8's sparsity fast paths; keep flags stay in LDS.
__global__ __launch_bounds__(256) void k_greedyout(
    const ull* __restrict__ maskmat, const unsigned short* __restrict__ nzmap,
    const int* __restrict__ det_valid, const float* __restrict__ topk_score,
    const float* __restrict__ det_box, const int* __restrict__ det_label,
    float* __restrict__ out) {
  __shared__ int keepsh[MROWS];
  int b = blockIdx.x;
  int tid = threadIdx.x;
  if (tid < 64) {
    int lane = tid;
    int wl = lane & 15;
    int grp = lane >> 4;
    const ull* mrow = maskmat + (size_t)b * MROWS * 16;
    ull rr[16];
    unsigned nzr[16];
#pragma unroll
    for (int k = 0; k < 16; ++k) {
      int row = k * 64 + lane;
      rr[k] = mrow[(size_t)row * 16 + k];
      unsigned nz = nzmap[b * MROWS + row];
      if (row >= KTOP) { rr[k] = 0ull; nz = 0u; }
      nzr[k] = nz & ~(1u << k);
    }
    ull validw = 0;
#pragma unroll
    for (int w = 0; w < 16; ++w) {
      int j = w * 64 + lane;
      int f = (j < KTOP) ? det_valid[b * KTOP + j] : 0;
      ull m = __ballot(f != 0);
      if (lane == w) validw = m;
    }
    ull supp = ~shfl64(validw, wl);
    for (int w = 0; w < 16; ++w) {
      int t0 = w * 64;
      int row = t0 + lane;
      ull inc = shfl64(supp, w);
      unsigned s32 = (unsigned)((inc >> lane) & 1ull);
      ull r = rr[w];
      if (__ballot(r != 0ull)) {
#pragma unroll
        for (int dd = 0; dd < 6; ++dd) {
          const int d = 1 << dd;
          const ull M0 = (dd == 0) ? 0x5555555555555555ull
                       : (dd == 1) ? 0x3333333333333333ull
                       : (dd == 2) ? 0x0F0F0F0F0F0F0F0Full
                       : (dd == 3) ? 0x00FF00FF00FF00FFull
                       : (dd == 4) ? 0x0000FFFF0000FFFFull
                                   : 0x00000000FFFFFFFFull;
          ull y = shfl_xor64(r, d);
          r = ((lane & d) == 0) ? ((r & M0) | ((y & M0) << d))
                                : ((r & ~M0) | ((y >> d) & M0));
        }
#pragma unroll
        for (int i = 0; i < 64; ++i) {
          ull act = __ballot(s32 == 0);
          s32 |= (unsigned)(((act & r) >> i) & 1ull);
        }
      }
      ull K = __ballot(s32 == 0);
      keepsh[row] = (row < KTOP && s32 == 0) ? 1 : 0;
      if (__ballot((((K >> lane) & 1ull) != 0ull) && (nzr[w] != 0u))) {
        ull acc = 0;
        int base_r = grp * 16;
#pragma unroll
        for (int k = 0; k < 16; ++k) {
          int i = base_r + k;
          ull v = mrow[(size_t)(t0 + i) * 16 + wl];
          if ((K >> i) & 1ull) acc |= v;
        }
        acc |= shfl_xor64(acc, 16);
        acc |= shfl_xor64(acc, 32);
        supp |= acc;
      }
    }
  }
  __syncthreads();

  // output emit: prefix scan of keepsh, first 100 kept -> out, zero-pad rest
  __shared__ int pf[MROWS];
  for (int i = tid; i < MROWS; i += 256) pf[i] = keepsh[i];
  __syncthreads();
  for (int d = 1; d < MROWS; d <<= 1) {
    int v[4];
#pragma unroll
    for (int k = 0; k < 4; ++k) {
      int i = tid + k * 256;
      v[k] = pf[i] + ((i >= d) ? pf[i - d] : 0);
    }
    __syncthreads();
#pragma unroll
    for (int k = 0; k < 4; ++k) pf[tid + k * 256] = v[k];
    __syncthreads();
  }
  int total = min(pf[KTOP - 1], NDET);
  float* ob = out;
  float* os = out + (size_t)NB * NDET * 4;
  float* ol = os + (size_t)NB * NDET;
  for (int i = tid; i < KTOP; i += 256) {
    if (keepsh[i]) {
      int r = pf[i] - 1;
      if (r < NDET) {
        ob[((size_t)b * NDET + r) * 4 + 0] = det_box[((size_t)b * KTOP + i) * 4 + 0];
        ob[((size_t)b * NDET + r) * 4 + 1] = det_box[((size_t)b * KTOP + i) * 4 + 1];
        ob[((size_t)b * NDET + r) * 4 + 2] = det_box[((size_t)b * KTOP + i) * 4 + 2];
        ob[((size_t)b * NDET + r) * 4 + 3] = det_box[((size_t)b * KTOP + i) * 4 + 3];
        os[b * NDET + r] = topk_score[b * KTOP + i];
        ol[b * NDET + r] = (float)det_label[b * KTOP + i];
      }
    }
  }
  for (int r = total + tid; r < NDET; r += 256) {
    ob[((size_t)b * NDET + r) * 4 + 0] = 0.0f;
    ob[((size_t)b * NDET + r) * 4 + 1] = 0.0f;
    ob[((size_t)b * NDET + r) * 4 + 2] = 0.0f;
    ob[((size_t)b * NDET + r) * 4 + 3] = 0.0f;
    os[b * NDET + r] = 0.0f;
    ol[b * NDET + r] = 0.0f;
  }
}

}  // namespace

extern "C" void kernel_launch(void* const* d_in, const int* in_sizes, int n_in,
                              void* d_out, int out_size, void* d_ws, size_t ws_size,
                              hipStream_t stream) {
  const float* logits = (const float*)d_in[0];
  const float* boxreg = (const float*)d_in[1];
  const float* props = (const float*)d_in[2];
  const int* hw = (const int*)d_in[3];

  char* ws = (char*)d_ws;
  size_t off = 0;
  auto alloc = [&](size_t bytes) -> void* {
    void* p = ws + off;
    off += (bytes + 255) & ~(size_t)255;
    return p;
  };
  ull* keys = (ull*)alloc((size_t)NB * NP * SLOTS * 8);
  int* pcount = (int*)alloc((size_t)NB * NP * 4);
  int* ghist = (int*)alloc((size_t)NB * NBUCK * 4);
  int* ccur = (int*)alloc((size_t)NB * NBUCK * 4);
  int* cstart = (int*)alloc((size_t)NB * NBUCK * 4);
  int* sboundA = (int*)alloc(NB * 4);
  int* ctotal = (int*)alloc(NB * 4);
  ull* ckeys = (ull*)alloc((size_t)NB * SORTN * 8);
  float* topk_score = (float*)alloc((size_t)NB * KTOP * 4);
  float* det_box = (float*)alloc((size_t)NB * KTOP * 16);
  int* det_label = (int*)alloc((size_t)NB * KTOP * 4);
  int* det_valid = (int*)alloc((size_t)NB * KTOP * 4);
  ull* maskmat = (ull*)alloc((size_t)NB * MROWS * 16 * 8);
  unsigned short* nzmap = (unsigned short*)alloc((size_t)NB * MROWS * 2);

  k_zero<<<(NB * NBUCK + 255) / 256, 256, 0, stream>>>(ghist);
  k_candidates<<<(NB * NP) / 16, 256, 0, stream>>>(logits, boxreg, props, hw,
                                                   keys, pcount, ghist);
  k_bound<<<NB, 1024, 0, stream>>>(ghist, ccur, cstart, sboundA, ctotal);
  k_compact<<<(NB * NP) / 256, 256, 0, stream>>>(keys, pcount, sboundA, ccur, ckeys);
  k_rankdec<<<NB, 1024, 0, stream>>>(ckeys, ctotal, cstart, ccur, boxreg, props, hw,
                                     topk_score, det_box, det_label, det_valid);
  k_mask<<<(NB * KTOP * 16 + 255) / 256, 256, 0, stream>>>(det_box, det_label, maskmat, nzmap);
  k_greedyout<<<NB, 256, 0, stream>>>(maskmat, nzmap, det_valid, topk_score,
                                      det_box, det_label, (float*)d_out);
}

// Round 10
// 111.512 us; speedup vs baseline: 2.0353x; 1.0683x over previous
//
#include <hip/hip_runtime.h>

namespace {

constexpr int NB = 8, NP = 8192, NC = 91;
constexpr int KTOP = 1000, NDET = 100;
constexpr int MROWS = 1024;          // padded mask rows per image (16 windows of 64)
constexpr int SLOTS = 24;            // max candidates/proposal: scores sum<=1 => <=19 can be >0.05
constexpr int NBUCK = 4096, SORTN = 4096;
constexpr float SCORE_T = 0.05f;
constexpr float MIN_SZ = 0.01f;
constexpr float NMS_T = 0.5f;
constexpr float CLIPV = 4.135166556742356f;  // log(1000/16)
constexpr float NEGV = -1e9f;

typedef unsigned long long ull;

__device__ __forceinline__ void decode_box(const float4& pr, const float4& rel,
                                           float Wf, float Hf,
                                           float& x1, float& y1, float& x2, float& y2) {
  float w = pr.z - pr.x, h = pr.w - pr.y;
  float cx = pr.x + 0.5f * w, cy = pr.y + 0.5f * h;
  float dx = rel.x / 10.0f, dy = rel.y / 10.0f;
  float dw = fminf(rel.z / 5.0f, CLIPV), dh = fminf(rel.w / 5.0f, CLIPV);
  float pcx = dx * w + cx, pcy = dy * h + cy;
  float pw = expf(dw) * w, ph = expf(dh) * h;
  x1 = fminf(fmaxf(pcx - 0.5f * pw, 0.0f), Wf);
  y1 = fminf(fmaxf(pcy - 0.5f * ph, 0.0f), Hf);
  x2 = fminf(fmaxf(pcx + 0.5f * pw, 0.0f), Wf);
  y2 = fminf(fmaxf(pcy + 0.5f * ph, 0.0f), Hf);
}

__device__ __forceinline__ int score_bucket(unsigned bits) {
  return min((int)((bits - 0x3D000000u) >> 14), NBUCK - 1);
}

__device__ __forceinline__ ull shfl64(ull v, int src) {
  int lo = __shfl((int)(unsigned)(v & 0xffffffffull), src, 64);
  int hi = __shfl((int)(unsigned)(v >> 32), src, 64);
  return ((ull)(unsigned)hi << 32) | (unsigned)lo;
}

__device__ __forceinline__ ull shfl_xor64(ull v, int d) {
  int lo = __shfl_xor((int)(unsigned)(v & 0xffffffffull), d, 64);
  int hi = __shfl_xor((int)(unsigned)(v >> 32), d, 64);
  return ((ull)(unsigned)hi << 32) | (unsigned)lo;
}

// 16-lane group per proposal; 16 proposals per 256-thread block staged through
// 5.8KB LDS (float4-coalesced). Logit-domain prefilter (strict superset,
// -1e-3 margin) gates the exact score test. Deterministic 24-slot region per
// proposal; NO global atomics at all (histogram moved into k_select).
__global__ __launch_bounds__(256) void k_candidates(
    const float* __restrict__ logits, const float* __restrict__ boxreg,
    const float* __restrict__ props, const int* __restrict__ hw,
    ull* __restrict__ keys, int* __restrict__ pcount) {
  __shared__ float sh[16 * NC];              // 1456 floats
  int tid = threadIdx.x;
  int base = blockIdx.x * 16;
  const float4* src4 = reinterpret_cast<const float4*>(logits + (size_t)base * NC);
  float4* sh4 = reinterpret_cast<float4*>(sh);
  for (int i = tid; i < (16 * NC) / 4; i += 256) sh4[i] = src4[i];
  __syncthreads();

  int lane = tid & 63;
  int l16 = lane & 15;
  int grp = lane >> 4;
  int wv = tid >> 6;
  int lp = wv * 4 + grp;                     // local proposal 0..15
  int gw = base + lp;
  int p = gw & (NP - 1);
  float Hf = (float)hw[0], Wf = (float)hw[1];
  const float* row = sh + lp * NC;

  float zreg[6];
  float m = -3.0e38f;
#pragma unroll
  for (int k = 0; k < 6; ++k) {
    int c = k * 16 + l16;
    float z = (c < NC) ? row[c] : -3.0e38f;
    zreg[k] = z;
    m = fmaxf(m, z);
  }
#pragma unroll
  for (int d = 1; d < 16; d <<= 1) m = fmaxf(m, __shfl_xor(m, d, 64));
  float S = 0.0f;
#pragma unroll
  for (int k = 0; k < 6; ++k) {
    int c = k * 16 + l16;
    S += (c < NC) ? expf(zreg[k] - m) : 0.0f;
  }
#pragma unroll
  for (int d = 1; d < 16; d <<= 1) S += __shfl_xor(S, d, 64);

  float invS = 1.0f / S;
  float thr = m + logf(SCORE_T * S) - 1e-3f;   // superset prefilter

  float4 pr = reinterpret_cast<const float4*>(props)[gw];
  const float4* relrow = reinterpret_cast<const float4*>(boxreg + (size_t)gw * 4 * NC);
  ull* krow = keys + (size_t)gw * SLOTS;
  unsigned below = (1u << l16) - 1u;
  int n = 0;
#pragma unroll
  for (int k = 0; k < 6; ++k) {
    int c = k * 16 + l16;
    bool ok = (c >= 1) && (c < NC) && (zreg[k] > thr);
    float sc = 0.0f;
    if (ok) {
      sc = expf(zreg[k] - m) * invS;
      ok = sc > SCORE_T;
      if (ok) {
        float4 rel = relrow[c];
        float x1, y1, x2, y2;
        decode_box(pr, rel, Wf, Hf, x1, y1, x2, y2);
        ok = ((x2 - x1) >= MIN_SZ) && ((y2 - y1) >= MIN_SZ);
      }
    }
    ull bal = __ballot(ok);
    unsigned gm = (unsigned)((bal >> (grp * 16)) & 0xFFFFull);
    if (ok) {
      int pos = n + __popc(gm & below);
      unsigned bits = __float_as_uint(sc);
      int idx = p * (NC - 1) + (c - 1);
      if (pos < SLOTS) krow[pos] = ((ull)bits << 32) | (unsigned)(~(unsigned)idx);
    }
    n += __popc(gm);
  }
  if (l16 == 0) pcount[gw] = min(n, SLOTS);
}

// Fused per-image selection: LDS histogram over 4096 score buckets -> suffix
// scan -> threshold bucket -> LDS scatter (per-bucket LDS cursors) -> segmented
// rank (position = region_start + #greater region-mates; keys unique ->
// bijective) -> decode straight into det_*. One block per image, 64KB LDS.
__global__ __launch_bounds__(1024) void k_select(
    const ull* __restrict__ keys, const int* __restrict__ pcount,
    const float* __restrict__ boxreg, const float* __restrict__ props,
    const int* __restrict__ hw,
    float* __restrict__ topk_score, float* __restrict__ det_box,
    int* __restrict__ det_label, int* __restrict__ nvalid) {
  __shared__ int h[NBUCK];
  __shared__ int cur[NBUCK];
  __shared__ ull sk[SORTN];
  __shared__ int sbs;
  int b = blockIdx.x, tid = threadIdx.x;
#pragma unroll
  for (int k = 0; k < NBUCK / 1024; ++k) h[tid + k * 1024] = 0;
  if (tid == 0) sbs = 0;
  __syncthreads();
  // pass A: histogram from keys
  int pbase = b * NP;
  for (int pi = tid; pi < NP; pi += 1024) {
    int pp = pbase + pi;
    int n = pcount[pp];
    const ull* krow = keys + (size_t)pp * SLOTS;
    for (int s = 0; s < n; ++s)
      atomicAdd(&h[score_bucket((unsigned)(krow[s] >> 32))], 1);
  }
  __syncthreads();
  // inclusive suffix scan: h[i] = count of candidates in buckets >= i
  for (int d = 1; d < NBUCK; d <<= 1) {
    int v[NBUCK / 1024];
#pragma unroll
    for (int k = 0; k < NBUCK / 1024; ++k) {
      int i = tid + k * 1024;
      v[k] = h[i] + ((i + d < NBUCK) ? h[i + d] : 0);
    }
    __syncthreads();
#pragma unroll
    for (int k = 0; k < NBUCK / 1024; ++k) h[tid + k * 1024] = v[k];
    __syncthreads();
  }
#pragma unroll
  for (int k = 0; k < NBUCK / 1024; ++k) {
    int i = tid + k * 1024;
    if (h[i] >= KTOP && (i == NBUCK - 1 || h[i + 1] < KTOP)) sbs = i;
  }
  __syncthreads();
#pragma unroll
  for (int k = 0; k < NBUCK / 1024; ++k) {
    int i = tid + k * 1024;
    cur[i] = (i + 1 < NBUCK) ? h[i + 1] : 0;   // region starts -> working cursors
  }
  __syncthreads();
  int sb = sbs;
  int total = min(h[sb], SORTN);
  // pass B: scatter keys >= threshold bucket into sk at per-bucket cursors
  for (int pi = tid; pi < NP; pi += 1024) {
    int pp = pbase + pi;
    int n = pcount[pp];
    const ull* krow = keys + (size_t)pp * SLOTS;
    for (int s = 0; s < n; ++s) {
      ull key = krow[s];
      int bk = score_bucket((unsigned)(key >> 32));
      if (bk < sb) continue;
      int pos = atomicAdd(&cur[bk], 1);
      if (pos < SORTN) sk[pos] = key;
    }
  }
  __syncthreads();
  // rank + decode
  float Hf = (float)hw[0], Wf = (float)hw[1];
  for (int i = tid; i < total; i += 1024) {
    ull key = sk[i];
    int bk = score_bucket((unsigned)(key >> 32));
    int s = (bk + 1 < NBUCK) ? h[bk + 1] : 0;
    int e = min(cur[bk], total);
    int r = s;
    for (int j = s; j < e; ++j) r += (sk[j] > key) ? 1 : 0;
    if (r < KTOP) {
      int g = b * KTOP + r;
      topk_score[g] = __uint_as_float((unsigned)(key >> 32));
      int fidx = (int)(~(unsigned)key);
      int p = fidx / (NC - 1), c = fidx % (NC - 1) + 1;
      float4 pr = reinterpret_cast<const float4*>(props)[b * NP + p];
      float4 rel =
          reinterpret_cast<const float4*>(boxreg + (size_t)(b * NP + p) * 4 * NC)[c];
      float x1, y1, x2, y2;
      decode_box(pr, rel, Wf, Hf, x1, y1, x2, y2);
      det_box[(size_t)g * 4 + 0] = x1;
      det_box[(size_t)g * 4 + 1] = y1;
      det_box[(size_t)g * 4 + 2] = x2;
      det_box[(size_t)g * 4 + 3] = y2;
      det_label[g] = c;
    }
  }
  int valid_n = min(total, KTOP);
  for (int r = valid_n + tid; r < KTOP; r += 1024) {
    int g = b * KTOP + r;
    topk_score[g] = NEGV;
    det_box[(size_t)g * 4 + 0] = 0.0f;
    det_box[(size_t)g * 4 + 1] = 0.0f;
    det_box[(size_t)g * 4 + 2] = 0.0f;
    det_box[(size_t)g * 4 + 3] = 0.0f;
    det_label[g] = 0;
  }
  if (tid == 0) nvalid[b] = valid_n;
}

// Suppression bit-matrix (labels-equal == class-offset NMS exactly, since
// offset_scale=1334 > max coord 1333 makes cross-class IoU 0) + per-row 16-bit
// nonzero-word bitmap (nzmap) via 16-lane ballot. Invalid rows have label 0 and
// zero boxes -> IoU 0 -> no edges (same as before).
__global__ __launch_bounds__(256) void k_mask(
    const float* __restrict__ det_box, const int* __restrict__ det_label,
    ull* __restrict__ maskmat, unsigned short* __restrict__ nzmap) {
  int g = blockIdx.x * 256 + threadIdx.x;   // grid exact: NB*KTOP*16 = 128000
  int w = g & 15;
  int i = (g >> 4) % KTOP;
  int b = (g >> 4) / KTOP;
  const float4* bb = reinterpret_cast<const float4*>(det_box) + (size_t)b * KTOP;
  const int* ll = det_label + b * KTOP;
  float4 bi = bb[i];
  int li = ll[i];
  float areai = (bi.z - bi.x) * (bi.w - bi.y);
  ull bits = 0;
  int j0 = w * 64;
  for (int t = 0; t < 64; ++t) {
    int j = j0 + t;
    if (j > i && j < KTOP && ll[j] == li) {
      float4 bj = bb[j];
      float areaj = (bj.z - bj.x) * (bj.w - bj.y);
      float ltx = fmaxf(bi.x, bj.x), lty = fmaxf(bi.y, bj.y);
      float rbx = fminf(bi.z, bj.z), rby = fminf(bi.w, bj.w);
      float iw = fmaxf(rbx - ltx, 0.0f), ih = fmaxf(rby - lty, 0.0f);
      float inter = iw * ih;
      float iou = inter / (areai + areaj - inter + 1e-9f);
      if (iou > NMS_T) bits |= (1ull << t);
    }
  }
  maskmat[((size_t)b * MROWS + i) * 16 + w] = bits;
  ull bal = __ballot(bits != 0ull);
  if (w == 0)
    nzmap[b * MROWS + i] = (unsigned short)((bal >> (threadIdx.x & 48)) & 0xFFFFull);
}

// Fused windowed greedy NMS (wave 0, sparsity fast paths) + output emit
// (all 256 threads). Validity is arithmetic: row < nvalid[b].
__global__ __launch_bounds__(256) void k_greedyout(
    const ull* __restrict__ maskmat, const unsigned short* __restrict__ nzmap,
    const int* __restrict__ nvalid, const float* __restrict__ topk_score,
    const float* __restrict__ det_box, const int* __restrict__ det_label,
    float* __restrict__ out) {
  __shared__ int keepsh[MROWS];
  int b = blockIdx.x;
  int tid = threadIdx.x;
  int nv = nvalid[b];
  if (tid < 64) {
    int lane = tid;
    int wl = lane & 15;
    int grp = lane >> 4;
    const ull* mrow = maskmat + (size_t)b * MROWS * 16;
    ull rr[16];
    unsigned nzr[16];
#pragma unroll
    for (int k = 0; k < 16; ++k) {
      int row = k * 64 + lane;
      rr[k] = mrow[(size_t)row * 16 + k];
      unsigned nz = nzmap[b * MROWS + row];
      if (row >= KTOP) { rr[k] = 0ull; nz = 0u; }
      nzr[k] = nz & ~(1u << k);
    }
    // valid word wl: rows wl*64 .. wl*64+63 valid iff < nv
    int lo = nv - wl * 64;
    ull vw = (lo >= 64) ? ~0ull : ((lo <= 0) ? 0ull : ((1ull << lo) - 1ull));
    ull supp = ~vw;
    for (int w = 0; w < 16; ++w) {
      int t0 = w * 64;
      int row = t0 + lane;
      ull inc = shfl64(supp, w);
      unsigned s32 = (unsigned)((inc >> lane) & 1ull);
      ull r = rr[w];
      if (__ballot(r != 0ull)) {
#pragma unroll
        for (int dd = 0; dd < 6; ++dd) {
          const int d = 1 << dd;
          const ull M0 = (dd == 0) ? 0x5555555555555555ull
                       : (dd == 1) ? 0x3333333333333333ull
                       : (dd == 2) ? 0x0F0F0F0F0F0F0F0Full
                       : (dd == 3) ? 0x00FF00FF00FF00FFull
                       : (dd == 4) ? 0x0000FFFF0000FFFFull
                                   : 0x00000000FFFFFFFFull;
          ull y = shfl_xor64(r, d);
          r = ((lane & d) == 0) ? ((r & M0) | ((y & M0) << d))
                                : ((r & ~M0) | ((y >> d) & M0));
        }
#pragma unroll
        for (int i = 0; i < 64; ++i) {
          ull act = __ballot(s32 == 0);
          s32 |= (unsigned)(((act & r) >> i) & 1ull);
        }
      }
      ull K = __ballot(s32 == 0);
      keepsh[row] = (row < KTOP && s32 == 0) ? 1 : 0;
      if (__ballot((((K >> lane) & 1ull) != 0ull) && (nzr[w] != 0u))) {
        ull acc = 0;
        int base_r = grp * 16;
#pragma unroll
        for (int k = 0; k < 16; ++k) {
          int i = base_r + k;
          ull v = mrow[(size_t)(t0 + i) * 16 + wl];
          if ((K >> i) & 1ull) acc |= v;
        }
        acc |= shfl_xor64(acc, 16);
        acc |= shfl_xor64(acc, 32);
        supp |= acc;
      }
    }
  }
  __syncthreads();

  __shared__ int pf[MROWS];
  for (int i = tid; i < MROWS; i += 256) pf[i] = keepsh[i];
  __syncthreads();
  for (int d = 1; d < MROWS; d <<= 1) {
    int v[4];
#pragma unroll
    for (int k = 0; k < 4; ++k) {
      int i = tid + k * 256;
      v[k] = pf[i] + ((i >= d) ? pf[i - d] : 0);
    }
    __syncthreads();
#pragma unroll
    for (int k = 0; k < 4; ++k) pf[tid + k * 256] = v[k];
    __syncthreads();
  }
  int total = min(pf[KTOP - 1], NDET);
  float* ob = out;
  float* os = out + (size_t)NB * NDET * 4;
  float* ol = os + (size_t)NB * NDET;
  for (int i = tid; i < KTOP; i += 256) {
    if (keepsh[i]) {
      int r = pf[i] - 1;
      if (r < NDET) {
        ob[((size_t)b * NDET + r) * 4 + 0] = det_box[((size_t)b * KTOP + i) * 4 + 0];
        ob[((size_t)b * NDET + r) * 4 + 1] = det_box[((size_t)b * KTOP + i) * 4 + 1];
        ob[((size_t)b * NDET + r) * 4 + 2] = det_box[((size_t)b * KTOP + i) * 4 + 2];
        ob[((size_t)b * NDET + r) * 4 + 3] = det_box[((size_t)b * KTOP + i) * 4 + 3];
        os[b * NDET + r] = topk_score[b * KTOP + i];
        ol[b * NDET + r] = (float)det_label[b * KTOP + i];
      }
    }
  }
  for (int r = total + tid; r < NDET; r += 256) {
    ob[((size_t)b * NDET + r) * 4 + 0] = 0.0f;
    ob[((size_t)b * NDET + r) * 4 + 1] = 0.0f;
    ob[((size_t)b * NDET + r) * 4 + 2] = 0.0f;
    ob[((size_t)b * NDET + r) * 4 + 3] = 0.0f;
    os[b * NDET + r] = 0.0f;
    ol[b * NDET + r] = 0.0f;
  }
}

}  // namespace

extern "C" void kernel_launch(void* const* d_in, const int* in_sizes, int n_in,
                              void* d_out, int out_size, void* d_ws, size_t ws_size,
                              hipStream_t stream) {
  const float* logits = (const float*)d_in[0];
  const float* boxreg = (const float*)d_in[1];
  const float* props = (const float*)d_in[2];
  const int* hw = (const int*)d_in[3];

  char* ws = (char*)d_ws;
  size_t off = 0;
  auto alloc = [&](size_t bytes) -> void* {
    void* p = ws + off;
    off += (bytes + 255) & ~(size_t)255;
    return p;
  };
  ull* keys = (ull*)alloc((size_t)NB * NP * SLOTS * 8);
  int* pcount = (int*)alloc((size_t)NB * NP * 4);
  float* topk_score = (float*)alloc((size_t)NB * KTOP * 4);
  float* det_box = (float*)alloc((size_t)NB * KTOP * 16);
  int* det_label = (int*)alloc((size_t)NB * KTOP * 4);
  int* nvalid = (int*)alloc(NB * 4);
  ull* maskmat = (ull*)alloc((size_t)NB * MROWS * 16 * 8);
  unsigned short* nzmap = (unsigned short*)alloc((size_t)NB * MROWS * 2);

  k_candidates<<<(NB * NP) / 16, 256, 0, stream>>>(logits, boxreg, props, hw,
                                                   keys, pcount);
  k_select<<<NB, 1024, 0, stream>>>(keys, pcount, boxreg, props, hw,
                                    topk_score, det_box, det_label, nvalid);
  k_mask<<<(NB * KTOP * 16) / 256, 256, 0, stream>>>(det_box, det_label, maskmat, nzmap);
  k_greedyout<<<NB, 256, 0, stream>>>(maskmat, nzmap, nvalid, topk_score,
                                      det_box, det_label, (float*)d_out);
}